// Round 2
// baseline (11985.595 us; speedup 1.0000x reference)
//
#include <hip/hip_runtime.h>

#define NTX 100000
#define NUSER 20000
#define NMERCH 5000
#define HD 256

using u16 = unsigned short;

__device__ __forceinline__ u16 f2bf(float f){
  unsigned u = __float_as_uint(f);
  unsigned r = (u + 0x7FFFu + ((u >> 16) & 1u)) >> 16;
  return (u16)r;
}
__device__ __forceinline__ float bf2f(u16 b){
  return __uint_as_float(((unsigned)b) << 16);
}

// ---------------- utility ----------------
__global__ __launch_bounds__(256) void zero_kernel(float* __restrict__ p, int n){
  int i = blockIdx.x*256 + threadIdx.x;
  if (i < n) p[i] = 0.f;
}

__global__ __launch_bounds__(256) void count_kernel(const int* __restrict__ dst, int n, float* __restrict__ cnt){
  int i = blockIdx.x*256 + threadIdx.x;
  if (i < n) unsafeAtomicAdd(&cnt[dst[i]], 1.0f);
}

__global__ __launch_bounds__(256) void invert_kernel(float* __restrict__ c, int n){
  int i = blockIdx.x*256 + threadIdx.x;
  if (i < n) c[i] = 1.0f / fmaxf(c[i], 1.0f);
}

// W02[l] = Wr[l,0]+Wr[l,2]; WH = [Wc1 | Wv1]; bH = [bc1 | bv1]
__global__ __launch_bounds__(256) void build_w_kernel(const float* __restrict__ Wr, const float* __restrict__ Wc1,
    const float* __restrict__ Wv1, const float* __restrict__ bc1, const float* __restrict__ bv1,
    float* __restrict__ w0, float* __restrict__ w1, float* __restrict__ WH, float* __restrict__ bH){
  int i = blockIdx.x*256 + threadIdx.x;
  if (i < 65536){
    w0[i] = Wr[i]         + Wr[2*65536 + i];
    w1[i] = Wr[4*65536+i] + Wr[6*65536 + i];
    int k = i >> 8, j = i & 255;
    WH[i] = (j < 128) ? Wc1[k*128 + j] : Wv1[k*128 + (j-128)];
    if (i < 256) bH[i] = (i < 128) ? bc1[i] : bv1[i-128];
  }
}

// f32 -> bf16 copy (×4 per thread)
__global__ __launch_bounds__(256) void cvt_kernel(const float* __restrict__ in, u16* __restrict__ out, int n4){
  int i = blockIdx.x*256 + threadIdx.x;
  if (i >= n4) return;
  float4 v = ((const float4*)in)[i];
  ushort4 o; o.x = f2bf(v.x); o.y = f2bf(v.y); o.z = f2bf(v.z); o.w = f2bf(v.w);
  ((ushort4*)out)[i] = o;
}

// relu(f32) -> bf16
__global__ __launch_bounds__(256) void relucvt_kernel(const float* __restrict__ in, u16* __restrict__ out, int n4){
  int i = blockIdx.x*256 + threadIdx.x;
  if (i >= n4) return;
  float4 v = ((const float4*)in)[i];
  ushort4 o;
  o.x = f2bf(fmaxf(v.x, 0.f)); o.y = f2bf(fmaxf(v.y, 0.f));
  o.z = f2bf(fmaxf(v.z, 0.f)); o.w = f2bf(fmaxf(v.w, 0.f));
  ((ushort4*)out)[i] = o;
}

// XT = bf16(relu(0.5*(ACC + b0 + b2)))
__global__ __launch_bounds__(256) void finalize2_kernel(const float* __restrict__ ACC, u16* __restrict__ XT,
    const float* __restrict__ b0, const float* __restrict__ b2, int n4){
  int i = blockIdx.x*256 + threadIdx.x;
  if (i >= n4) return;
  int j = (i & 63) << 2;
  float4 v = ((const float4*)ACC)[i];
  ushort4 o;
  o.x = f2bf(fmaxf(0.5f*(v.x + b0[j+0] + b2[j+0]), 0.f));
  o.y = f2bf(fmaxf(0.5f*(v.y + b0[j+1] + b2[j+1]), 0.f));
  o.z = f2bf(fmaxf(0.5f*(v.z + b0[j+2] + b2[j+2]), 0.f));
  o.w = f2bf(fmaxf(0.5f*(v.w + b0[j+3] + b2[j+3]), 0.f));
  ((ushort4*)XT)[i] = o;
}

// ---------------- tiled GEMM: C (+)= act(A[MxK] @ W[KxN] (+ bias)) ----------------
// 64x64 tile, 256 threads, 4x4 microtile, K-step 16. K%16==0, N%64==0.
template<bool ABF, bool CBF, bool BIAS, bool RELU, bool ACCUM>
__global__ __launch_bounds__(256) void gemm_kernel(const void* __restrict__ Ap, const float* __restrict__ W,
    const float* __restrict__ bias, void* __restrict__ Cp, int M, int K, int N){
  __shared__ float As[16][68];   // [k][row]
  __shared__ float Ws[16][68];   // [k][col]
  int m0 = blockIdx.x * 64, n0 = blockIdx.y * 64;
  int t = threadIdx.x;
  int tx = t & 15, ty = t >> 4;
  int ar = t >> 2, ac = (t & 3) << 2;   // A load: row ar, k-offset ac
  int wr = t >> 4, wc = (t & 15) << 2;  // W load: k-row wr, col wc
  float acc[4][4] = {};
  for (int k0 = 0; k0 < K; k0 += 16){
    float a0=0.f, a1=0.f, a2=0.f, a3=0.f;
    int arow = m0 + ar;
    if (arow < M){
      if constexpr (ABF){
        const u16* A = (const u16*)Ap;
        ushort4 av = *(const ushort4*)(A + (size_t)arow*K + k0 + ac);
        a0 = bf2f(av.x); a1 = bf2f(av.y); a2 = bf2f(av.z); a3 = bf2f(av.w);
      } else {
        const float* A = (const float*)Ap;
        float4 av = *(const float4*)(A + (size_t)arow*K + k0 + ac);
        a0 = av.x; a1 = av.y; a2 = av.z; a3 = av.w;
      }
    }
    As[ac+0][ar] = a0; As[ac+1][ar] = a1; As[ac+2][ar] = a2; As[ac+3][ar] = a3;
    float4 wv = *(const float4*)(W + (size_t)(k0+wr)*N + n0 + wc);
    *(float4*)&Ws[wr][wc] = wv;
    __syncthreads();
    #pragma unroll
    for (int kk = 0; kk < 16; ++kk){
      float4 a = *(const float4*)&As[kk][ty<<2];
      float4 w = *(const float4*)&Ws[kk][tx<<2];
      acc[0][0] += a.x*w.x; acc[0][1] += a.x*w.y; acc[0][2] += a.x*w.z; acc[0][3] += a.x*w.w;
      acc[1][0] += a.y*w.x; acc[1][1] += a.y*w.y; acc[1][2] += a.y*w.z; acc[1][3] += a.y*w.w;
      acc[2][0] += a.z*w.x; acc[2][1] += a.z*w.y; acc[2][2] += a.z*w.z; acc[2][3] += a.z*w.w;
      acc[3][0] += a.w*w.x; acc[3][1] += a.w*w.y; acc[3][2] += a.w*w.z; acc[3][3] += a.w*w.w;
    }
    __syncthreads();
  }
  float bv[4] = {0.f,0.f,0.f,0.f};
  if constexpr (BIAS){
    bv[0] = bias[n0+(tx<<2)+0]; bv[1] = bias[n0+(tx<<2)+1];
    bv[2] = bias[n0+(tx<<2)+2]; bv[3] = bias[n0+(tx<<2)+3];
  }
  #pragma unroll
  for (int i = 0; i < 4; ++i){
    int row = m0 + (ty<<2) + i;
    if (row < M){
      float4 o;
      o.x = acc[i][0] + bv[0]; o.y = acc[i][1] + bv[1];
      o.z = acc[i][2] + bv[2]; o.w = acc[i][3] + bv[3];
      if constexpr (ACCUM){
        float4 c = *(const float4*)((const float*)Cp + (size_t)row*N + n0 + (tx<<2));
        o.x += c.x; o.y += c.y; o.z += c.z; o.w += c.w;
      }
      if constexpr (RELU){
        o.x = fmaxf(o.x,0.f); o.y = fmaxf(o.y,0.f); o.z = fmaxf(o.z,0.f); o.w = fmaxf(o.w,0.f);
      }
      if constexpr (CBF){
        ushort4 s; s.x = f2bf(o.x); s.y = f2bf(o.y); s.z = f2bf(o.z); s.w = f2bf(o.w);
        *(ushort4*)((u16*)Cp + (size_t)row*N + n0 + (tx<<2)) = s;
      } else {
        *(float4*)((float*)Cp + (size_t)row*N + n0 + (tx<<2)) = o;
      }
    }
  }
}

// ---------------- edge scatter: out[dst] += Y[src] * inv[dst] (f32 atomics) ----------------
template<bool YBF>
__global__ __launch_bounds__(256) void scatter_kernel(const void* __restrict__ Yp, const int* __restrict__ src,
    const int* __restrict__ dst, const float* __restrict__ inv, float* __restrict__ out, int nE){
  int e = blockIdx.x*4 + (threadIdx.x >> 6);
  if (e >= nE) return;
  int lane = threadIdx.x & 63;
  int s = src[e], d = dst[e];
  float sc = inv[d];
  float v0,v1,v2,v3;
  if constexpr (YBF){
    const u16* Y = (const u16*)Yp;
    ushort4 v = *(const ushort4*)(Y + (size_t)s*HD + (lane<<2));
    v0 = bf2f(v.x); v1 = bf2f(v.y); v2 = bf2f(v.z); v3 = bf2f(v.w);
  } else {
    const float* Y = (const float*)Yp;
    float4 v = ((const float4*)(Y + (size_t)s*HD))[lane];
    v0 = v.x; v1 = v.y; v2 = v.z; v3 = v.w;
  }
  float* o = out + (size_t)d*HD + (lane<<2);
  unsafeAtomicAdd(o+0, v0*sc);
  unsafeAtomicAdd(o+1, v1*sc);
  unsafeAtomicAdd(o+2, v2*sc);
  unsafeAtomicAdd(o+3, v3*sc);
}

// ---------------- head: two 128-dot products per row from ACC ----------------
__global__ __launch_bounds__(256) void head_kernel(const float* __restrict__ Hm, const float* __restrict__ Wc2,
    const float* __restrict__ bc2, const float* __restrict__ Wv2, const float* __restrict__ bv2,
    float* __restrict__ out, int M){
  int row = blockIdx.x*4 + (threadIdx.x >> 6);
  if (row >= M) return;
  int lane = threadIdx.x & 63;
  const float* h = Hm + (size_t)row*256;
  float s1 = h[lane]*Wc2[lane] + h[lane+64]*Wc2[lane+64];
  float s2 = h[128+lane]*Wv2[lane] + h[192+lane]*Wv2[lane+64];
  #pragma unroll
  for (int off = 32; off > 0; off >>= 1){
    s1 += __shfl_down(s1, off);
    s2 += __shfl_down(s2, off);
  }
  if (lane == 0){ out[row] = s1 + bc2[0]; out[M+row] = s2 + bv2[0]; }
}

extern "C" void kernel_launch(void* const* d_in, const int* in_sizes, int n_in,
                              void* d_out, int out_size, void* d_ws, size_t ws_size,
                              hipStream_t stream){
  const float* x_tx   = (const float*)d_in[0];
  const float* x_user = (const float*)d_in[1];
  const float* x_merch= (const float*)d_in[2];
  const float* Wp  = (const float*)d_in[3];
  const float* bp  = (const float*)d_in[4];
  const float* Wl  = (const float*)d_in[5];
  const float* bl  = (const float*)d_in[6];
  const float* Wr  = (const float*)d_in[7];
  const float* Wc1 = (const float*)d_in[8];
  const float* bc1 = (const float*)d_in[9];
  const float* Wc2 = (const float*)d_in[10];
  const float* bc2 = (const float*)d_in[11];
  const float* Wv1 = (const float*)d_in[12];
  const float* bv1 = (const float*)d_in[13];
  const float* Wv2 = (const float*)d_in[14];
  const float* bv2 = (const float*)d_in[15];
  const int* e_ut_s = (const int*)d_in[16];
  const int* e_ut_d = (const int*)d_in[17];
  const int* e_tm_s = (const int*)d_in[18];
  const int* e_tm_d = (const int*)d_in[19];
  const int* e_mt_s = (const int*)d_in[20];
  const int* e_mt_d = (const int*)d_in[21];
  const int* e_tu_s = (const int*)d_in[22];
  const int* e_tu_d = (const int*)d_in[23];
  float* out = (float*)d_out;
  const int NE = in_sizes[16];

  // ---- workspace layout (bytes, 256B-aligned starts), total ~224.4 MB ----
  char* p = (char*)d_ws;
  auto take = [&](size_t bytes)->char*{ char* r = p; p += (bytes + 255) & ~(size_t)255; return r; };
  u16*   XT   = (u16*)  take((size_t)NTX*HD*2);        // 51.2 MB   bf16 tx activations (in-place per layer)
  float* ACC  = (float*)take((size_t)NTX*HD*4);        // 102.4 MB  f32 tx accumulator / head hidden
  float* R1   = (float*)take((size_t)25000*HD*4);      // 25.6 MB   T_u(20000)+T_m(5000) OR UOUT(20000)
  float* AGGU = (float*)take((size_t)NUSER*HD*4);      // 20.5 MB
  float* AGGM = (float*)take((size_t)NMERCH*HD*4);     // 5.1 MB
  float* MOUT = (float*)take((size_t)NMERCH*HD*4);     // 5.1 MB
  u16*   XU   = (u16*)  take((size_t)NUSER*HD*2);      // 10.2 MB
  u16*   XM   = (u16*)  take((size_t)NMERCH*HD*2);     // 2.6 MB
  float* CNT  = (float*)take((size_t)225000*4);        // 0.9 MB
  float* W02_0= (float*)take((size_t)65536*4);
  float* W02_1= (float*)take((size_t)65536*4);
  float* WH   = (float*)take((size_t)65536*4);
  float* bH   = (float*)take((size_t)256*4);
  float* inv_ut = CNT, *inv_tm = CNT+100000, *inv_mt = CNT+105000, *inv_tu = CNT+205000;

  // ---- degrees (recomputed every call; CNT must be re-zeroed for graph replay) ----
  zero_kernel<<<(225000+255)/256,256,0,stream>>>(CNT, 225000);
  int cgrid = (NE + 255)/256;
  count_kernel<<<cgrid,256,0,stream>>>(e_ut_d, NE, inv_ut);
  count_kernel<<<cgrid,256,0,stream>>>(e_tm_d, NE, inv_tm);
  count_kernel<<<cgrid,256,0,stream>>>(e_mt_d, NE, inv_mt);
  count_kernel<<<cgrid,256,0,stream>>>(e_tu_d, NE, inv_tu);
  invert_kernel<<<(225000+255)/256,256,0,stream>>>(CNT, 225000);
  build_w_kernel<<<(65536+255)/256,256,0,stream>>>(Wr, Wc1, Wv1, bc1, bv1, W02_0, W02_1, WH, bH);

  auto g2 = [](int M, int N){ return dim3((unsigned)((M+63)/64), (unsigned)(N/64)); };
  int sgrid = (NE + 3)/4;

  // ---- init activations ----
  // XT = bf16(x_tx @ Wp + bp)
  gemm_kernel<false,true,true,false,false><<<g2(NTX,HD),256,0,stream>>>(x_tx, Wp, bp, XT, NTX, 32, HD);
  cvt_kernel<<<(NUSER*HD/4+255)/256,256,0,stream>>>(x_user, XU, NUSER*HD/4);
  cvt_kernel<<<(NMERCH*HD/4+255)/256,256,0,stream>>>(x_merch, XM, NMERCH*HD/4);

  for (int l = 0; l < 2; ++l){
    const float* Wl_l = Wl + (size_t)l*4*65536;
    const float* Wr_l = Wr + (size_t)l*4*65536;
    const float* bl_l = bl + (size_t)l*4*256;
    const float* w02  = (l == 0) ? W02_0 : W02_1;
    float* T_u = R1;                 // 20000 rows
    float* T_m = R1 + (size_t)20000*HD; // 5000 rows
    float* UOUT = R1;                // reused after T consumed

    // aggregate-first: AGGM = segmean_tm(XT), AGGU = segmean_tu(XT)  (reads OLD XT)
    zero_kernel<<<((NUSER+NMERCH)*HD+255)/256,256,0,stream>>>(AGGU, (NUSER+NMERCH)*HD);
    scatter_kernel<true><<<sgrid,256,0,stream>>>(XT, e_tm_s, e_tm_d, inv_tm, AGGM, NE);
    scatter_kernel<true><<<sgrid,256,0,stream>>>(XT, e_tu_s, e_tu_d, inv_tu, AGGU, NE);

    // transform-first: T_u = XU@Wl0, T_m = XM@Wl2 (reads OLD XU/XM)
    gemm_kernel<true,false,false,false,false><<<g2(NUSER,HD),256,0,stream>>>(XU, Wl_l + 0*65536, nullptr, T_u, NUSER, HD, HD);
    gemm_kernel<true,false,false,false,false><<<g2(NMERCH,HD),256,0,stream>>>(XM, Wl_l + 2*65536, nullptr, T_m, NMERCH, HD, HD);

    // tx root + scatters: ACC = XT@(Wr0+Wr2) ; ACC += scat_ut(T_u) + scat_mt(T_m)
    gemm_kernel<true,false,false,false,false><<<g2(NTX,HD),256,0,stream>>>(XT, w02, nullptr, ACC, NTX, HD, HD);
    scatter_kernel<false><<<sgrid,256,0,stream>>>(T_u, e_ut_s, e_ut_d, inv_ut, ACC, NE);
    scatter_kernel<false><<<sgrid,256,0,stream>>>(T_m, e_mt_s, e_mt_d, inv_mt, ACC, NE);
    // XT = bf16(relu(0.5*(ACC + bl0 + bl2)))   (all reads of old XT done)
    finalize2_kernel<<<(NTX*HD/4+255)/256,256,0,stream>>>(ACC, XT, bl_l + 0*256, bl_l + 2*256, NTX*HD/4);

    // merchant: MOUT = AGGM@Wl1 + bl1 ; MOUT += XM@Wr1 ; XM = bf16(relu(MOUT))
    gemm_kernel<false,false,true,false,false><<<g2(NMERCH,HD),256,0,stream>>>(AGGM, Wl_l + 1*65536, bl_l + 1*256, MOUT, NMERCH, HD, HD);
    gemm_kernel<true,false,false,false,true><<<g2(NMERCH,HD),256,0,stream>>>(XM, Wr_l + 1*65536, nullptr, MOUT, NMERCH, HD, HD);
    relucvt_kernel<<<(NMERCH*HD/4+255)/256,256,0,stream>>>(MOUT, XM, NMERCH*HD/4);

    // user: UOUT = AGGU@Wl3 + bl3 ; UOUT += XU@Wr3 ; XU = bf16(relu(UOUT))
    gemm_kernel<false,false,true,false,false><<<g2(NUSER,HD),256,0,stream>>>(AGGU, Wl_l + 3*65536, bl_l + 3*256, UOUT, NUSER, HD, HD);
    gemm_kernel<true,false,false,false,true><<<g2(NUSER,HD),256,0,stream>>>(XU, Wr_l + 3*65536, nullptr, UOUT, NUSER, HD, HD);
    relucvt_kernel<<<(NUSER*HD/4+255)/256,256,0,stream>>>(UOUT, XU, NUSER*HD/4);
  }

  // heads: ACC = relu(XT @ [Wc1|Wv1] + [bc1|bv1]); then two 128-dots per row
  gemm_kernel<true,false,true,true,false><<<g2(NTX,HD),256,0,stream>>>(XT, WH, bH, ACC, NTX, HD, HD);
  head_kernel<<<(NTX+3)/4,256,0,stream>>>(ACC, Wc2, bc2, Wv2, bv2, out, NTX);
}

// Round 3
// 1758.358 us; speedup vs baseline: 6.8164x; 6.8164x over previous
//
#include <hip/hip_runtime.h>

#define NTX 100000
#define NUSER 20000
#define NMERCH 5000
#define HD 256

using u16 = unsigned short;

__device__ __forceinline__ u16 f2bf(float f){
  unsigned u = __float_as_uint(f);
  unsigned r = (u + 0x7FFFu + ((u >> 16) & 1u)) >> 16;
  return (u16)r;
}
__device__ __forceinline__ float bf2f(u16 b){
  return __uint_as_float(((unsigned)b) << 16);
}

// ---------------- small utilities ----------------
__global__ __launch_bounds__(256) void zero_int_kernel(int* __restrict__ p, int n){
  int i = blockIdx.x*256 + threadIdx.x;
  if (i < n) p[i] = 0;
}

__global__ __launch_bounds__(256) void count_int_kernel(const int* __restrict__ dst, int n, int* __restrict__ cnt){
  int i = blockIdx.x*256 + threadIdx.x;
  if (i < n) atomicAdd(&cnt[dst[i]], 1);
}

// per-block (1024 elems) reduction of counts -> bsum[b]
__global__ __launch_bounds__(256) void block_reduce_kernel(const int* __restrict__ cnt, int n, int* __restrict__ bsum){
  __shared__ int sh[256];
  int b = blockIdx.x, t = threadIdx.x;
  int base = b*1024;
  int v = 0;
  for (int i = t; i < 1024; i += 256){ int idx = base + i; if (idx < n) v += cnt[idx]; }
  sh[t] = v; __syncthreads();
  for (int o = 128; o > 0; o >>= 1){ if (t < o) sh[t] += sh[t+o]; __syncthreads(); }
  if (t == 0) bsum[b] = sh[0];
}

// serial exclusive scan of bsum (nb <= 128), also write rowptr[n] = total
__global__ void scan_small_kernel(int* __restrict__ bsum, int nb, int* __restrict__ rowptr, int n, int total){
  if (threadIdx.x == 0 && blockIdx.x == 0){
    int run = 0;
    for (int i = 0; i < nb; ++i){ int v = bsum[i]; bsum[i] = run; run += v; }
    rowptr[n] = total;
  }
}

// per-block exclusive scan over 1024 counts + block offset; also inv[d]=1/max(cnt,1)
__global__ __launch_bounds__(256) void scan_block_kernel(const int* __restrict__ cnt, int n,
    const int* __restrict__ bsum, int* __restrict__ rowptr, float* __restrict__ inv){
  __shared__ int sh[256];
  int b = blockIdx.x, t = threadIdx.x;
  int base = b*1024 + t*4;
  int c0=0,c1=0,c2=0,c3=0;
  if (base+0 < n) c0 = cnt[base+0];
  if (base+1 < n) c1 = cnt[base+1];
  if (base+2 < n) c2 = cnt[base+2];
  if (base+3 < n) c3 = cnt[base+3];
  int local = c0+c1+c2+c3;
  sh[t] = local; __syncthreads();
  for (int o = 1; o < 256; o <<= 1){
    int v = (t >= o) ? sh[t-o] : 0;
    __syncthreads();
    sh[t] += v;
    __syncthreads();
  }
  int ex = bsum[b] + sh[t] - local;
  if (base+0 < n){ rowptr[base+0] = ex;          inv[base+0] = 1.f/fmaxf((float)c0,1.f); }
  if (base+1 < n){ rowptr[base+1] = ex+c0;       inv[base+1] = 1.f/fmaxf((float)c1,1.f); }
  if (base+2 < n){ rowptr[base+2] = ex+c0+c1;    inv[base+2] = 1.f/fmaxf((float)c2,1.f); }
  if (base+3 < n){ rowptr[base+3] = ex+c0+c1+c2; inv[base+3] = 1.f/fmaxf((float)c3,1.f); }
}

__global__ __launch_bounds__(256) void fill_csr_kernel(const int* __restrict__ src, const int* __restrict__ dst,
    const int* __restrict__ rowptr, int* __restrict__ cursor, int* __restrict__ ssrc, int nE){
  int e = blockIdx.x*256 + threadIdx.x;
  if (e < nE){
    int d = dst[e];
    int pos = atomicAdd(&cursor[d], 1);
    ssrc[rowptr[d] + pos] = src[e];
  }
}

// W02[l] = Wr[l,0]+Wr[l,2]; WH = [Wc1 | Wv1]; bH = [bc1 | bv1]
__global__ __launch_bounds__(256) void build_w_kernel(const float* __restrict__ Wr, const float* __restrict__ Wc1,
    const float* __restrict__ Wv1, const float* __restrict__ bc1, const float* __restrict__ bv1,
    float* __restrict__ w0, float* __restrict__ w1, float* __restrict__ WH, float* __restrict__ bH){
  int i = blockIdx.x*256 + threadIdx.x;
  if (i < 65536){
    w0[i] = Wr[i]         + Wr[2*65536 + i];
    w1[i] = Wr[4*65536+i] + Wr[6*65536 + i];
    int k = i >> 8, j = i & 255;
    WH[i] = (j < 128) ? Wc1[k*128 + j] : Wv1[k*128 + (j-128)];
    if (i < 256) bH[i] = (i < 128) ? bc1[i] : bv1[i-128];
  }
}

// f32 -> bf16
__global__ __launch_bounds__(256) void cvt_kernel(const float* __restrict__ in, u16* __restrict__ out, int n4){
  int i = blockIdx.x*256 + threadIdx.x;
  if (i >= n4) return;
  float4 v = ((const float4*)in)[i];
  ushort4 o; o.x = f2bf(v.x); o.y = f2bf(v.y); o.z = f2bf(v.z); o.w = f2bf(v.w);
  ((ushort4*)out)[i] = o;
}

// relu(f32) -> bf16
__global__ __launch_bounds__(256) void relucvt_kernel(const float* __restrict__ in, u16* __restrict__ out, int n4){
  int i = blockIdx.x*256 + threadIdx.x;
  if (i >= n4) return;
  float4 v = ((const float4*)in)[i];
  ushort4 o;
  o.x = f2bf(fmaxf(v.x, 0.f)); o.y = f2bf(fmaxf(v.y, 0.f));
  o.z = f2bf(fmaxf(v.z, 0.f)); o.w = f2bf(fmaxf(v.w, 0.f));
  ((ushort4*)out)[i] = o;
}

// ---------------- tiled GEMM: C (+)= act(A[MxK] @ W[KxN] (+ bias)) ----------------
template<bool ABF, bool CBF, bool BIAS, bool RELU, bool ACCUM>
__global__ __launch_bounds__(256) void gemm_kernel(const void* __restrict__ Ap, const float* __restrict__ W,
    const float* __restrict__ bias, void* __restrict__ Cp, int M, int K, int N){
  __shared__ float As[16][68];
  __shared__ float Ws[16][68];
  int m0 = blockIdx.x * 64, n0 = blockIdx.y * 64;
  int t = threadIdx.x;
  int tx = t & 15, ty = t >> 4;
  int ar = t >> 2, ac = (t & 3) << 2;
  int wr = t >> 4, wc = (t & 15) << 2;
  float acc[4][4] = {};
  for (int k0 = 0; k0 < K; k0 += 16){
    float a0=0.f, a1=0.f, a2=0.f, a3=0.f;
    int arow = m0 + ar;
    if (arow < M){
      if constexpr (ABF){
        const u16* A = (const u16*)Ap;
        ushort4 av = *(const ushort4*)(A + (size_t)arow*K + k0 + ac);
        a0 = bf2f(av.x); a1 = bf2f(av.y); a2 = bf2f(av.z); a3 = bf2f(av.w);
      } else {
        const float* A = (const float*)Ap;
        float4 av = *(const float4*)(A + (size_t)arow*K + k0 + ac);
        a0 = av.x; a1 = av.y; a2 = av.z; a3 = av.w;
      }
    }
    As[ac+0][ar] = a0; As[ac+1][ar] = a1; As[ac+2][ar] = a2; As[ac+3][ar] = a3;
    float4 wv = *(const float4*)(W + (size_t)(k0+wr)*N + n0 + wc);
    *(float4*)&Ws[wr][wc] = wv;
    __syncthreads();
    #pragma unroll
    for (int kk = 0; kk < 16; ++kk){
      float4 a = *(const float4*)&As[kk][ty<<2];
      float4 w = *(const float4*)&Ws[kk][tx<<2];
      acc[0][0] += a.x*w.x; acc[0][1] += a.x*w.y; acc[0][2] += a.x*w.z; acc[0][3] += a.x*w.w;
      acc[1][0] += a.y*w.x; acc[1][1] += a.y*w.y; acc[1][2] += a.y*w.z; acc[1][3] += a.y*w.w;
      acc[2][0] += a.z*w.x; acc[2][1] += a.z*w.y; acc[2][2] += a.z*w.z; acc[2][3] += a.z*w.w;
      acc[3][0] += a.w*w.x; acc[3][1] += a.w*w.y; acc[3][2] += a.w*w.z; acc[3][3] += a.w*w.w;
    }
    __syncthreads();
  }
  float bv[4] = {0.f,0.f,0.f,0.f};
  if constexpr (BIAS){
    bv[0] = bias[n0+(tx<<2)+0]; bv[1] = bias[n0+(tx<<2)+1];
    bv[2] = bias[n0+(tx<<2)+2]; bv[3] = bias[n0+(tx<<2)+3];
  }
  #pragma unroll
  for (int i = 0; i < 4; ++i){
    int row = m0 + (ty<<2) + i;
    if (row < M){
      float4 o;
      o.x = acc[i][0] + bv[0]; o.y = acc[i][1] + bv[1];
      o.z = acc[i][2] + bv[2]; o.w = acc[i][3] + bv[3];
      if constexpr (ACCUM){
        float4 c = *(const float4*)((const float*)Cp + (size_t)row*N + n0 + (tx<<2));
        o.x += c.x; o.y += c.y; o.z += c.z; o.w += c.w;
      }
      if constexpr (RELU){
        o.x = fmaxf(o.x,0.f); o.y = fmaxf(o.y,0.f); o.z = fmaxf(o.z,0.f); o.w = fmaxf(o.w,0.f);
      }
      if constexpr (CBF){
        ushort4 s; s.x = f2bf(o.x); s.y = f2bf(o.y); s.z = f2bf(o.z); s.w = f2bf(o.w);
        *(ushort4*)((u16*)Cp + (size_t)row*N + n0 + (tx<<2)) = s;
      } else {
        *(float4*)((float*)Cp + (size_t)row*N + n0 + (tx<<2)) = o;
      }
    }
  }
}

// ---------------- gather-mean: out[d] = inv[d] * sum_{j} X[ssrc[j]]  (bf16 src, f32 out) ----------------
__global__ __launch_bounds__(256) void gather_mean_kernel(const u16* __restrict__ X,
    const int* __restrict__ rp, const int* __restrict__ ss, const float* __restrict__ inv,
    float* __restrict__ out, int M){
  int d = blockIdx.x*4 + (threadIdx.x >> 6);
  if (d >= M) return;
  int lane = threadIdx.x & 63;
  int c = lane << 2;
  int j0 = rp[d], j1 = rp[d+1];
  float a0=0.f,a1=0.f,a2=0.f,a3=0.f;
  for (int j = j0; j < j1; ++j){
    ushort4 v = *(const ushort4*)(X + (size_t)ss[j]*HD + c);
    a0 += bf2f(v.x); a1 += bf2f(v.y); a2 += bf2f(v.z); a3 += bf2f(v.w);
  }
  float sc = inv[d];
  float4 o; o.x = a0*sc; o.y = a1*sc; o.z = a2*sc; o.w = a3*sc;
  *(float4*)(out + (size_t)d*HD + c) = o;
}

// ---------------- fused tx epilogue: XT = bf16(relu(0.5*(ACCb + mean_ut(Tu) + mean_mt(Tm) + b0 + b2))) ----
__global__ __launch_bounds__(256) void fused_tx_kernel(const u16* __restrict__ ACCb,
    const u16* __restrict__ Tu, const u16* __restrict__ Tm,
    const int* __restrict__ rpu, const int* __restrict__ ssu, const float* __restrict__ invu,
    const int* __restrict__ rpm, const int* __restrict__ ssm, const float* __restrict__ invm,
    const float* __restrict__ b0, const float* __restrict__ b2, u16* __restrict__ XT, int M){
  int d = blockIdx.x*4 + (threadIdx.x >> 6);
  if (d >= M) return;
  int lane = threadIdx.x & 63;
  int c = lane << 2;
  ushort4 av = *(const ushort4*)(ACCb + (size_t)d*HD + c);
  float r0 = bf2f(av.x), r1 = bf2f(av.y), r2 = bf2f(av.z), r3 = bf2f(av.w);
  {
    int j0 = rpu[d], j1 = rpu[d+1];
    float s0=0.f,s1=0.f,s2=0.f,s3=0.f;
    for (int j = j0; j < j1; ++j){
      ushort4 v = *(const ushort4*)(Tu + (size_t)ssu[j]*HD + c);
      s0 += bf2f(v.x); s1 += bf2f(v.y); s2 += bf2f(v.z); s3 += bf2f(v.w);
    }
    float sc = invu[d];
    r0 += s0*sc; r1 += s1*sc; r2 += s2*sc; r3 += s3*sc;
  }
  {
    int j0 = rpm[d], j1 = rpm[d+1];
    float s0=0.f,s1=0.f,s2=0.f,s3=0.f;
    for (int j = j0; j < j1; ++j){
      ushort4 v = *(const ushort4*)(Tm + (size_t)ssm[j]*HD + c);
      s0 += bf2f(v.x); s1 += bf2f(v.y); s2 += bf2f(v.z); s3 += bf2f(v.w);
    }
    float sc = invm[d];
    r0 += s0*sc; r1 += s1*sc; r2 += s2*sc; r3 += s3*sc;
  }
  float4 bb0 = *(const float4*)(b0 + c);
  float4 bb2 = *(const float4*)(b2 + c);
  ushort4 o;
  o.x = f2bf(fmaxf(0.5f*(r0 + bb0.x + bb2.x), 0.f));
  o.y = f2bf(fmaxf(0.5f*(r1 + bb0.y + bb2.y), 0.f));
  o.z = f2bf(fmaxf(0.5f*(r2 + bb0.z + bb2.z), 0.f));
  o.w = f2bf(fmaxf(0.5f*(r3 + bb0.w + bb2.w), 0.f));
  *(ushort4*)(XT + (size_t)d*HD + c) = o;
}

// ---------------- head: two 128-dot products per row (bf16 hidden) ----------------
__global__ __launch_bounds__(256) void head_kernel(const u16* __restrict__ Hm, const float* __restrict__ Wc2,
    const float* __restrict__ bc2, const float* __restrict__ Wv2, const float* __restrict__ bv2,
    float* __restrict__ out, int M){
  int row = blockIdx.x*4 + (threadIdx.x >> 6);
  if (row >= M) return;
  int lane = threadIdx.x & 63;
  const u16* h = Hm + (size_t)row*256;
  float s1 = bf2f(h[lane])*Wc2[lane] + bf2f(h[lane+64])*Wc2[lane+64];
  float s2 = bf2f(h[128+lane])*Wv2[lane] + bf2f(h[192+lane])*Wv2[lane+64];
  #pragma unroll
  for (int off = 32; off > 0; off >>= 1){
    s1 += __shfl_down(s1, off);
    s2 += __shfl_down(s2, off);
  }
  if (lane == 0){ out[row] = s1 + bc2[0]; out[M+row] = s2 + bv2[0]; }
}

extern "C" void kernel_launch(void* const* d_in, const int* in_sizes, int n_in,
                              void* d_out, int out_size, void* d_ws, size_t ws_size,
                              hipStream_t stream){
  const float* x_tx   = (const float*)d_in[0];
  const float* x_user = (const float*)d_in[1];
  const float* x_merch= (const float*)d_in[2];
  const float* Wp  = (const float*)d_in[3];
  const float* bp  = (const float*)d_in[4];
  const float* Wl  = (const float*)d_in[5];
  const float* bl  = (const float*)d_in[6];
  const float* Wr  = (const float*)d_in[7];
  const float* Wc1 = (const float*)d_in[8];
  const float* bc1 = (const float*)d_in[9];
  const float* Wc2 = (const float*)d_in[10];
  const float* bc2 = (const float*)d_in[11];
  const float* Wv1 = (const float*)d_in[12];
  const float* bv1 = (const float*)d_in[13];
  const float* Wv2 = (const float*)d_in[14];
  const float* bv2 = (const float*)d_in[15];
  const int* e_ut_s = (const int*)d_in[16];
  const int* e_ut_d = (const int*)d_in[17];
  const int* e_tm_s = (const int*)d_in[18];
  const int* e_tm_d = (const int*)d_in[19];
  const int* e_mt_s = (const int*)d_in[20];
  const int* e_mt_d = (const int*)d_in[21];
  const int* e_tu_s = (const int*)d_in[22];
  const int* e_tu_d = (const int*)d_in[23];
  float* out = (float*)d_out;
  const int NE = in_sizes[16];

  // ---- workspace layout (~183 MB) ----
  char* p = (char*)d_ws;
  auto take = [&](size_t bytes)->char*{ char* r = p; p += (bytes + 255) & ~(size_t)255; return r; };
  u16*   XT    = (u16*)  take((size_t)NTX*HD*2);        // 51.2 MB  bf16 tx activations
  u16*   ACCb  = (u16*)  take((size_t)NTX*HD*2);        // 51.2 MB  bf16 root-term / head hidden
  char*  R1    =         take((size_t)25000*HD*4);      // 25.6 MB  Tu(bf16)+Tm(bf16) then UOUT(f32)
  float* AGGU  = (float*)take((size_t)NUSER*HD*4);      // 20.5 MB
  float* AGGM  = (float*)take((size_t)NMERCH*HD*4);     // 5.1 MB
  float* MOUT  = (float*)take((size_t)NMERCH*HD*4);     // 5.1 MB
  u16*   XU    = (u16*)  take((size_t)NUSER*HD*2);      // 10.2 MB
  u16*   XM    = (u16*)  take((size_t)NMERCH*HD*2);     // 2.6 MB
  int*   CNT   = (int*)  take((size_t)225000*4);        // counts (per-relation segments)
  int*   CUR   = (int*)  take((size_t)225000*4);        // fill cursors
  float* INV   = (float*)take((size_t)225000*4);        // 1/max(cnt,1)
  int*   RP    = (int*)  take((size_t)225008*4);        // rowptrs (n+1 each)
  int*   SS_ut = (int*)  take((size_t)400000*4);
  int*   SS_tm = (int*)  take((size_t)400000*4);
  int*   SS_mt = (int*)  take((size_t)400000*4);
  int*   SS_tu = (int*)  take((size_t)400000*4);
  int*   BS    = (int*)  take((size_t)4*128*4);         // per-relation block sums
  float* W02_0 = (float*)take((size_t)65536*4);
  float* W02_1 = (float*)take((size_t)65536*4);
  float* WH    = (float*)take((size_t)65536*4);
  float* bH    = (float*)take((size_t)256*4);

  // per-relation segment offsets: ut(dst=tx,100000), tm(dst=merch,5000), mt(dst=tx,100000), tu(dst=user,20000)
  int*   cnt_ut = CNT,        *cnt_tm = CNT+100000, *cnt_mt = CNT+105000, *cnt_tu = CNT+205000;
  int*   cur_ut = CUR,        *cur_tm = CUR+100000, *cur_mt = CUR+105000, *cur_tu = CUR+205000;
  float* inv_ut = INV,        *inv_tm = INV+100000, *inv_mt = INV+105000, *inv_tu = INV+205000;
  int*   rp_ut  = RP,         *rp_tm  = RP+100001,  *rp_mt  = RP+105002,  *rp_tu  = RP+205003;
  int*   bs_ut  = BS,         *bs_tm  = BS+128,     *bs_mt  = BS+256,     *bs_tu  = BS+384;

  // ---- CSR build (per call; deterministic given inputs) ----
  zero_int_kernel<<<(225000+255)/256,256,0,stream>>>(CNT, 225000);
  zero_int_kernel<<<(225000+255)/256,256,0,stream>>>(CUR, 225000);
  int egrid = (NE + 255)/256;
  count_int_kernel<<<egrid,256,0,stream>>>(e_ut_d, NE, cnt_ut);
  count_int_kernel<<<egrid,256,0,stream>>>(e_tm_d, NE, cnt_tm);
  count_int_kernel<<<egrid,256,0,stream>>>(e_mt_d, NE, cnt_mt);
  count_int_kernel<<<egrid,256,0,stream>>>(e_tu_d, NE, cnt_tu);
  auto nb = [](int n){ return (n + 1023)/1024; };
  block_reduce_kernel<<<nb(NTX),256,0,stream>>>(cnt_ut, NTX, bs_ut);
  block_reduce_kernel<<<nb(NMERCH),256,0,stream>>>(cnt_tm, NMERCH, bs_tm);
  block_reduce_kernel<<<nb(NTX),256,0,stream>>>(cnt_mt, NTX, bs_mt);
  block_reduce_kernel<<<nb(NUSER),256,0,stream>>>(cnt_tu, NUSER, bs_tu);
  scan_small_kernel<<<1,1,0,stream>>>(bs_ut, nb(NTX), rp_ut, NTX, NE);
  scan_small_kernel<<<1,1,0,stream>>>(bs_tm, nb(NMERCH), rp_tm, NMERCH, NE);
  scan_small_kernel<<<1,1,0,stream>>>(bs_mt, nb(NTX), rp_mt, NTX, NE);
  scan_small_kernel<<<1,1,0,stream>>>(bs_tu, nb(NUSER), rp_tu, NUSER, NE);
  scan_block_kernel<<<nb(NTX),256,0,stream>>>(cnt_ut, NTX, bs_ut, rp_ut, inv_ut);
  scan_block_kernel<<<nb(NMERCH),256,0,stream>>>(cnt_tm, NMERCH, bs_tm, rp_tm, inv_tm);
  scan_block_kernel<<<nb(NTX),256,0,stream>>>(cnt_mt, NTX, bs_mt, rp_mt, inv_mt);
  scan_block_kernel<<<nb(NUSER),256,0,stream>>>(cnt_tu, NUSER, bs_tu, rp_tu, inv_tu);
  fill_csr_kernel<<<egrid,256,0,stream>>>(e_ut_s, e_ut_d, rp_ut, cur_ut, SS_ut, NE);
  fill_csr_kernel<<<egrid,256,0,stream>>>(e_tm_s, e_tm_d, rp_tm, cur_tm, SS_tm, NE);
  fill_csr_kernel<<<egrid,256,0,stream>>>(e_mt_s, e_mt_d, rp_mt, cur_mt, SS_mt, NE);
  fill_csr_kernel<<<egrid,256,0,stream>>>(e_tu_s, e_tu_d, rp_tu, cur_tu, SS_tu, NE);
  build_w_kernel<<<(65536+255)/256,256,0,stream>>>(Wr, Wc1, Wv1, bc1, bv1, W02_0, W02_1, WH, bH);

  auto g2 = [](int M, int N){ return dim3((unsigned)((M+63)/64), (unsigned)(N/64)); };

  // ---- init activations ----
  gemm_kernel<false,true,true,false,false><<<g2(NTX,HD),256,0,stream>>>(x_tx, Wp, bp, XT, NTX, 32, HD);
  cvt_kernel<<<(NUSER*HD/4+255)/256,256,0,stream>>>(x_user, XU, NUSER*HD/4);
  cvt_kernel<<<(NMERCH*HD/4+255)/256,256,0,stream>>>(x_merch, XM, NMERCH*HD/4);

  for (int l = 0; l < 2; ++l){
    const float* Wl_l = Wl + (size_t)l*4*65536;
    const float* Wr_l = Wr + (size_t)l*4*65536;
    const float* bl_l = bl + (size_t)l*4*256;
    const float* w02  = (l == 0) ? W02_0 : W02_1;
    u16* Tu = (u16*)R1;
    u16* Tm = (u16*)R1 + (size_t)20000*HD;
    float* UOUT = (float*)R1;   // reused after Tu/Tm consumed

    // inbound means of OLD XT into user/merchant
    gather_mean_kernel<<<(NMERCH+3)/4,256,0,stream>>>(XT, rp_tm, SS_tm, inv_tm, AGGM, NMERCH);
    gather_mean_kernel<<<(NUSER+3)/4,256,0,stream>>>(XT, rp_tu, SS_tu, inv_tu, AGGU, NUSER);

    // transform-first for tx inbound (reads OLD XU/XM)
    gemm_kernel<true,true,false,false,false><<<g2(NUSER,HD),256,0,stream>>>(XU, Wl_l + 0*65536, nullptr, Tu, NUSER, HD, HD);
    gemm_kernel<true,true,false,false,false><<<g2(NMERCH,HD),256,0,stream>>>(XM, Wl_l + 2*65536, nullptr, Tm, NMERCH, HD, HD);

    // tx root term, then fused gather+epilogue -> new XT
    gemm_kernel<true,true,false,false,false><<<g2(NTX,HD),256,0,stream>>>(XT, w02, nullptr, ACCb, NTX, HD, HD);
    fused_tx_kernel<<<(NTX+3)/4,256,0,stream>>>(ACCb, Tu, Tm,
        rp_ut, SS_ut, inv_ut, rp_mt, SS_mt, inv_mt,
        bl_l + 0*256, bl_l + 2*256, XT, NTX);

    // merchant: MOUT = AGGM@Wl1 + bl1 ; MOUT += XM@Wr1 ; XM = bf16(relu(MOUT))
    gemm_kernel<false,false,true,false,false><<<g2(NMERCH,HD),256,0,stream>>>(AGGM, Wl_l + 1*65536, bl_l + 1*256, MOUT, NMERCH, HD, HD);
    gemm_kernel<true,false,false,false,true><<<g2(NMERCH,HD),256,0,stream>>>(XM, Wr_l + 1*65536, nullptr, MOUT, NMERCH, HD, HD);
    relucvt_kernel<<<(NMERCH*HD/4+255)/256,256,0,stream>>>(MOUT, XM, NMERCH*HD/4);

    // user: UOUT = AGGU@Wl3 + bl3 ; UOUT += XU@Wr3 ; XU = bf16(relu(UOUT))
    gemm_kernel<false,false,true,false,false><<<g2(NUSER,HD),256,0,stream>>>(AGGU, Wl_l + 3*65536, bl_l + 3*256, UOUT, NUSER, HD, HD);
    gemm_kernel<true,false,false,false,true><<<g2(NUSER,HD),256,0,stream>>>(XU, Wr_l + 3*65536, nullptr, UOUT, NUSER, HD, HD);
    relucvt_kernel<<<(NUSER*HD/4+255)/256,256,0,stream>>>(UOUT, XU, NUSER*HD/4);
  }

  // heads
  gemm_kernel<true,true,true,true,false><<<g2(NTX,HD),256,0,stream>>>(XT, WH, bH, ACCb, NTX, HD, HD);
  head_kernel<<<(NTX+3)/4,256,0,stream>>>(ACCb, Wc2, bc2, Wv2, bv2, out, NTX);
}

// Round 4
// 1106.311 us; speedup vs baseline: 10.8338x; 1.5894x over previous
//
#include <hip/hip_runtime.h>

#define NTX 100000
#define NUSER 20000
#define NMERCH 5000
#define HD 256
#define ROWPAD 128

using u16 = unsigned short;
typedef __attribute__((ext_vector_type(8))) short bf16x8;
typedef __attribute__((ext_vector_type(4))) float f32x4;

__device__ __forceinline__ u16 f2bf(float f){
  unsigned u = __float_as_uint(f);
  unsigned r = (u + 0x7FFFu + ((u >> 16) & 1u)) >> 16;
  return (u16)r;
}
__device__ __forceinline__ float bf2f(u16 b){
  return __uint_as_float(((unsigned)b) << 16);
}

// ---------------- small utilities ----------------
__global__ __launch_bounds__(256) void zero_int_kernel(int* __restrict__ p, int n){
  int i = blockIdx.x*256 + threadIdx.x;
  if (i < n) p[i] = 0;
}

__global__ __launch_bounds__(256) void count_int_kernel(const int* __restrict__ dst, int n, int* __restrict__ cnt){
  int i = blockIdx.x*256 + threadIdx.x;
  if (i < n) atomicAdd(&cnt[dst[i]], 1);
}

__global__ __launch_bounds__(256) void block_reduce_kernel(const int* __restrict__ cnt, int n, int* __restrict__ bsum){
  __shared__ int sh[256];
  int b = blockIdx.x, t = threadIdx.x;
  int base = b*1024;
  int v = 0;
  for (int i = t; i < 1024; i += 256){ int idx = base + i; if (idx < n) v += cnt[idx]; }
  sh[t] = v; __syncthreads();
  for (int o = 128; o > 0; o >>= 1){ if (t < o) sh[t] += sh[t+o]; __syncthreads(); }
  if (t == 0) bsum[b] = sh[0];
}

__global__ void scan_small_kernel(int* __restrict__ bsum, int nb, int* __restrict__ rowptr, int n, int total){
  if (threadIdx.x == 0 && blockIdx.x == 0){
    int run = 0;
    for (int i = 0; i < nb; ++i){ int v = bsum[i]; bsum[i] = run; run += v; }
    rowptr[n] = total;
  }
}

__global__ __launch_bounds__(256) void scan_block_kernel(const int* __restrict__ cnt, int n,
    const int* __restrict__ bsum, int* __restrict__ rowptr, float* __restrict__ inv){
  __shared__ int sh[256];
  int b = blockIdx.x, t = threadIdx.x;
  int base = b*1024 + t*4;
  int c0=0,c1=0,c2=0,c3=0;
  if (base+0 < n) c0 = cnt[base+0];
  if (base+1 < n) c1 = cnt[base+1];
  if (base+2 < n) c2 = cnt[base+2];
  if (base+3 < n) c3 = cnt[base+3];
  int local = c0+c1+c2+c3;
  sh[t] = local; __syncthreads();
  for (int o = 1; o < 256; o <<= 1){
    int v = (t >= o) ? sh[t-o] : 0;
    __syncthreads();
    sh[t] += v;
    __syncthreads();
  }
  int ex = bsum[b] + sh[t] - local;
  if (base+0 < n){ rowptr[base+0] = ex;          inv[base+0] = 1.f/fmaxf((float)c0,1.f); }
  if (base+1 < n){ rowptr[base+1] = ex+c0;       inv[base+1] = 1.f/fmaxf((float)c1,1.f); }
  if (base+2 < n){ rowptr[base+2] = ex+c0+c1;    inv[base+2] = 1.f/fmaxf((float)c2,1.f); }
  if (base+3 < n){ rowptr[base+3] = ex+c0+c1+c2; inv[base+3] = 1.f/fmaxf((float)c3,1.f); }
}

__global__ __launch_bounds__(256) void fill_csr_kernel(const int* __restrict__ src, const int* __restrict__ dst,
    const int* __restrict__ rowptr, int* __restrict__ cursor, int* __restrict__ ssrc, int nE){
  int e = blockIdx.x*256 + threadIdx.x;
  if (e < nE){
    int d = dst[e];
    int pos = atomicAdd(&cursor[d], 1);
    ssrc[rowptr[d] + pos] = src[e];
  }
}

// ---------------- weight prep: bf16 transposed WT[n][k] ----------------
__global__ __launch_bounds__(256) void tcvt_kernel(const float* __restrict__ W, u16* __restrict__ WT, int K, int N){
  int i = blockIdx.x*256 + threadIdx.x;
  if (i < K*N){ int k = i / N, n = i - k*N; WT[(size_t)n*K + k] = f2bf(W[i]); }
}

__global__ __launch_bounds__(256) void tcvt2_kernel(const float* __restrict__ W0, const float* __restrict__ W2,
    u16* __restrict__ WT, int K, int N){
  int i = blockIdx.x*256 + threadIdx.x;
  if (i < K*N){ int k = i / N, n = i - k*N; WT[(size_t)n*K + k] = f2bf(W0[i] + W2[i]); }
}

__global__ __launch_bounds__(256) void tcvtH_kernel(const float* __restrict__ Wc1, const float* __restrict__ Wv1,
    u16* __restrict__ WT, int K){
  int i = blockIdx.x*256 + threadIdx.x;
  if (i < K*256){
    int k = i >> 8, n = i & 255;
    float v = (n < 128) ? Wc1[k*128 + n] : Wv1[k*128 + (n-128)];
    WT[(size_t)n*K + k] = f2bf(v);
  }
}

__global__ void bh_kernel(const float* __restrict__ bc1, const float* __restrict__ bv1, float* __restrict__ bH){
  int i = threadIdx.x;
  bH[i] = (i < 128) ? bc1[i] : bv1[i-128];
}

// f32 -> bf16
__global__ __launch_bounds__(256) void cvt_kernel(const float* __restrict__ in, u16* __restrict__ out, int n4){
  int i = blockIdx.x*256 + threadIdx.x;
  if (i >= n4) return;
  float4 v = ((const float4*)in)[i];
  ushort4 o; o.x = f2bf(v.x); o.y = f2bf(v.y); o.z = f2bf(v.z); o.w = f2bf(v.w);
  ((ushort4*)out)[i] = o;
}

// ---------------- MFMA GEMM: C = epilogue(A[MxK]bf16 @ WT[NxK]bf16) ----------------
// 128x128 tile, BK=32, 256 threads = 4 waves (2x2), wave tile 64x64 = 4x4 mfma 16x16x32 frags.
// LDS rows padded +8 bf16 (16B) -> 2-way bank conflicts only (free).
template<bool CBF, bool BIAS, bool RELU, bool ACCUM>
__global__ __launch_bounds__(256) void mfma_gemm_kernel(const u16* __restrict__ A, const u16* __restrict__ BT,
    const float* __restrict__ bias, const float* __restrict__ Cadd, void* __restrict__ Cp, int M, int K, int N){
  __shared__ u16 As[128][40];
  __shared__ u16 Bs[128][40];
  int m0 = blockIdx.x * 128, n0 = blockIdx.y * 128;
  int t = threadIdx.x;
  int w = t >> 6, lane = t & 63;
  int wm = (w >> 1) << 6, wn = (w & 1) << 6;
  int lm = lane & 15;
  int lk = (lane >> 4) << 3;   // k offset of fragment (0,8,16,24)
  f32x4 acc[4][4] = {};

  // staging indices: chunk c in [0,512): row=c>>2, k-quad=(c&3)*8 ; thread does c=t and c=t+256
  int sr0 = t >> 2,        sk0 = (t & 3) << 3;
  int sr1 = (t+256) >> 2,  sk1 = sk0;

  for (int k0 = 0; k0 < K; k0 += 32){
    uint4 a0 = *(const uint4*)(A  + (size_t)(m0+sr0)*K + k0 + sk0);
    uint4 a1 = *(const uint4*)(A  + (size_t)(m0+sr1)*K + k0 + sk1);
    uint4 b0 = *(const uint4*)(BT + (size_t)(n0+sr0)*K + k0 + sk0);
    uint4 b1 = *(const uint4*)(BT + (size_t)(n0+sr1)*K + k0 + sk1);
    *(uint4*)&As[sr0][sk0] = a0;
    *(uint4*)&As[sr1][sk1] = a1;
    *(uint4*)&Bs[sr0][sk0] = b0;
    *(uint4*)&Bs[sr1][sk1] = b1;
    __syncthreads();
    bf16x8 af[4], bf[4];
    #pragma unroll
    for (int i = 0; i < 4; ++i) af[i] = *(const bf16x8*)&As[wm + i*16 + lm][lk];
    #pragma unroll
    for (int j = 0; j < 4; ++j) bf[j] = *(const bf16x8*)&Bs[wn + j*16 + lm][lk];
    #pragma unroll
    for (int i = 0; i < 4; ++i)
      #pragma unroll
      for (int j = 0; j < 4; ++j)
        acc[i][j] = __builtin_amdgcn_mfma_f32_16x16x32_bf16(af[i], bf[j], acc[i][j], 0, 0, 0);
    __syncthreads();
  }

  // epilogue: D row = (lane>>4)*4 + r, col = lane&15 within each 16x16 frag
  int rsub = (lane >> 4) << 2;
  #pragma unroll
  for (int j = 0; j < 4; ++j){
    int col = n0 + wn + j*16 + lm;
    float bv = 0.f;
    if constexpr (BIAS) bv = bias[col];
    #pragma unroll
    for (int i = 0; i < 4; ++i){
      int rbase = m0 + wm + i*16 + rsub;
      #pragma unroll
      for (int r = 0; r < 4; ++r){
        int row = rbase + r;
        if (row < M){
          float v = acc[i][j][r] + bv;
          if constexpr (ACCUM) v += Cadd[(size_t)row*N + col];
          if constexpr (RELU) v = fmaxf(v, 0.f);
          if constexpr (CBF) ((u16*)Cp)[(size_t)row*N + col] = f2bf(v);
          else               ((float*)Cp)[(size_t)row*N + col] = v;
        }
      }
    }
  }
}

// ---------------- gather-mean: out[d] = bf16(inv[d] * sum_j X[ss[j]]) ----------------
__global__ __launch_bounds__(256) void gather_mean_kernel(const u16* __restrict__ X,
    const int* __restrict__ rp, const int* __restrict__ ss, const float* __restrict__ inv,
    u16* __restrict__ out, int M){
  int d = blockIdx.x*4 + (threadIdx.x >> 6);
  if (d >= M) return;
  int lane = threadIdx.x & 63;
  int c = lane << 2;
  int j0 = rp[d], j1 = rp[d+1];
  float a0=0.f,a1=0.f,a2=0.f,a3=0.f;
  for (int j = j0; j < j1; ++j){
    ushort4 v = *(const ushort4*)(X + (size_t)ss[j]*HD + c);
    a0 += bf2f(v.x); a1 += bf2f(v.y); a2 += bf2f(v.z); a3 += bf2f(v.w);
  }
  float sc = inv[d];
  ushort4 o; o.x = f2bf(a0*sc); o.y = f2bf(a1*sc); o.z = f2bf(a2*sc); o.w = f2bf(a3*sc);
  *(ushort4*)(out + (size_t)d*HD + c) = o;
}

// ---------------- fused tx epilogue ----------------
__global__ __launch_bounds__(256) void fused_tx_kernel(const u16* __restrict__ ACCb,
    const u16* __restrict__ Tu, const u16* __restrict__ Tm,
    const int* __restrict__ rpu, const int* __restrict__ ssu, const float* __restrict__ invu,
    const int* __restrict__ rpm, const int* __restrict__ ssm, const float* __restrict__ invm,
    const float* __restrict__ b0, const float* __restrict__ b2, u16* __restrict__ XT, int M){
  int d = blockIdx.x*4 + (threadIdx.x >> 6);
  if (d >= M) return;
  int lane = threadIdx.x & 63;
  int c = lane << 2;
  ushort4 av = *(const ushort4*)(ACCb + (size_t)d*HD + c);
  float r0 = bf2f(av.x), r1 = bf2f(av.y), r2 = bf2f(av.z), r3 = bf2f(av.w);
  {
    int j0 = rpu[d], j1 = rpu[d+1];
    float s0=0.f,s1=0.f,s2=0.f,s3=0.f;
    for (int j = j0; j < j1; ++j){
      ushort4 v = *(const ushort4*)(Tu + (size_t)ssu[j]*HD + c);
      s0 += bf2f(v.x); s1 += bf2f(v.y); s2 += bf2f(v.z); s3 += bf2f(v.w);
    }
    float sc = invu[d];
    r0 += s0*sc; r1 += s1*sc; r2 += s2*sc; r3 += s3*sc;
  }
  {
    int j0 = rpm[d], j1 = rpm[d+1];
    float s0=0.f,s1=0.f,s2=0.f,s3=0.f;
    for (int j = j0; j < j1; ++j){
      ushort4 v = *(const ushort4*)(Tm + (size_t)ssm[j]*HD + c);
      s0 += bf2f(v.x); s1 += bf2f(v.y); s2 += bf2f(v.z); s3 += bf2f(v.w);
    }
    float sc = invm[d];
    r0 += s0*sc; r1 += s1*sc; r2 += s2*sc; r3 += s3*sc;
  }
  float4 bb0 = *(const float4*)(b0 + c);
  float4 bb2 = *(const float4*)(b2 + c);
  ushort4 o;
  o.x = f2bf(fmaxf(0.5f*(r0 + bb0.x + bb2.x), 0.f));
  o.y = f2bf(fmaxf(0.5f*(r1 + bb0.y + bb2.y), 0.f));
  o.z = f2bf(fmaxf(0.5f*(r2 + bb0.z + bb2.z), 0.f));
  o.w = f2bf(fmaxf(0.5f*(r3 + bb0.w + bb2.w), 0.f));
  *(ushort4*)(XT + (size_t)d*HD + c) = o;
}

// ---------------- head ----------------
__global__ __launch_bounds__(256) void head_kernel(const u16* __restrict__ Hm, const float* __restrict__ Wc2,
    const float* __restrict__ bc2, const float* __restrict__ Wv2, const float* __restrict__ bv2,
    float* __restrict__ out, int M){
  int row = blockIdx.x*4 + (threadIdx.x >> 6);
  if (row >= M) return;
  int lane = threadIdx.x & 63;
  const u16* h = Hm + (size_t)row*256;
  float s1 = bf2f(h[lane])*Wc2[lane] + bf2f(h[lane+64])*Wc2[lane+64];
  float s2 = bf2f(h[128+lane])*Wv2[lane] + bf2f(h[192+lane])*Wv2[lane+64];
  #pragma unroll
  for (int off = 32; off > 0; off >>= 1){
    s1 += __shfl_down(s1, off);
    s2 += __shfl_down(s2, off);
  }
  if (lane == 0){ out[row] = s1 + bc2[0]; out[M+row] = s2 + bv2[0]; }
}

extern "C" void kernel_launch(void* const* d_in, const int* in_sizes, int n_in,
                              void* d_out, int out_size, void* d_ws, size_t ws_size,
                              hipStream_t stream){
  const float* x_tx   = (const float*)d_in[0];
  const float* x_user = (const float*)d_in[1];
  const float* x_merch= (const float*)d_in[2];
  const float* Wp  = (const float*)d_in[3];
  const float* bp  = (const float*)d_in[4];
  const float* Wl  = (const float*)d_in[5];
  const float* bl  = (const float*)d_in[6];
  const float* Wr  = (const float*)d_in[7];
  const float* Wc1 = (const float*)d_in[8];
  const float* bc1 = (const float*)d_in[9];
  const float* Wc2 = (const float*)d_in[10];
  const float* bc2 = (const float*)d_in[11];
  const float* Wv1 = (const float*)d_in[12];
  const float* bv1 = (const float*)d_in[13];
  const float* Wv2 = (const float*)d_in[14];
  const float* bv2 = (const float*)d_in[15];
  const int* e_ut_s = (const int*)d_in[16];
  const int* e_ut_d = (const int*)d_in[17];
  const int* e_tm_s = (const int*)d_in[18];
  const int* e_tm_d = (const int*)d_in[19];
  const int* e_mt_s = (const int*)d_in[20];
  const int* e_mt_d = (const int*)d_in[21];
  const int* e_tu_s = (const int*)d_in[22];
  const int* e_tu_d = (const int*)d_in[23];
  float* out = (float*)d_out;
  const int NE = in_sizes[16];

  // ---- workspace layout (~181 MB) ----
  char* p = (char*)d_ws;
  auto take = [&](size_t bytes)->char*{ char* r = p; p += (bytes + 255) & ~(size_t)255; return r; };
  u16*   XT    = (u16*)  take((size_t)(NTX+ROWPAD)*HD*2);     // 51.3 MB
  u16*   ACCb  = (u16*)  take((size_t)(NTX+ROWPAD)*HD*2);     // 51.3 MB (also aliases XTin at start)
  char*  R1    =         take((size_t)NUSER*HD*4);            // 20.5 MB: Tu(bf16)+Tm(bf16), later UOUT(f32)
  u16*   AGGU  = (u16*)  take((size_t)(NUSER+ROWPAD)*HD*2);   // 10.3 MB
  u16*   AGGM  = (u16*)  take((size_t)(NMERCH+ROWPAD)*HD*2);  // 2.7 MB
  float* MOUT  = (float*)take((size_t)NMERCH*HD*4);           // 5.1 MB
  u16*   XU0   = (u16*)  take((size_t)(NUSER+ROWPAD)*HD*2);   // 10.3 MB
  u16*   XU1   = (u16*)  take((size_t)(NUSER+ROWPAD)*HD*2);   // 10.3 MB
  u16*   XM0   = (u16*)  take((size_t)(NMERCH+ROWPAD)*HD*2);  // 2.7 MB
  u16*   XM1   = (u16*)  take((size_t)(NMERCH+ROWPAD)*HD*2);  // 2.7 MB
  int*   CNT   = (int*)  take((size_t)225000*4);
  int*   CUR   = (int*)  take((size_t)225000*4);
  float* INV   = (float*)take((size_t)225000*4);
  int*   RP    = (int*)  take((size_t)225008*4);
  int*   SS_ut = (int*)  take((size_t)NE*4);
  int*   SS_tm = (int*)  take((size_t)NE*4);
  int*   SS_mt = (int*)  take((size_t)NE*4);
  int*   SS_tu = (int*)  take((size_t)NE*4);
  int*   BS    = (int*)  take((size_t)4*128*4);
  // bf16 transposed weights
  u16*   WTp   = (u16*)  take((size_t)32*256*2);
  u16*   WTl   = (u16*)  take((size_t)8*65536*2);   // [l][r][n][k]
  u16*   WTr1  = (u16*)  take((size_t)2*65536*2);
  u16*   WTr3  = (u16*)  take((size_t)2*65536*2);
  u16*   WT02  = (u16*)  take((size_t)2*65536*2);
  u16*   WTH   = (u16*)  take((size_t)65536*2);
  float* bH    = (float*)take((size_t)256*4);
  u16*   XTin  = ACCb;   // alias: [NTX+pad][32] bf16, consumed by proj before ACCb first written

  int*   cnt_ut = CNT,        *cnt_tm = CNT+100000, *cnt_mt = CNT+105000, *cnt_tu = CNT+205000;
  int*   cur_ut = CUR,        *cur_tm = CUR+100000, *cur_mt = CUR+105000, *cur_tu = CUR+205000;
  float* inv_ut = INV,        *inv_tm = INV+100000, *inv_mt = INV+105000, *inv_tu = INV+205000;
  int*   rp_ut  = RP,         *rp_tm  = RP+100001,  *rp_mt  = RP+105002,  *rp_tu  = RP+205003;
  int*   bs_ut  = BS,         *bs_tm  = BS+128,     *bs_mt  = BS+256,     *bs_tu  = BS+384;

  // ---- CSR build ----
  zero_int_kernel<<<(225000+255)/256,256,0,stream>>>(CNT, 225000);
  zero_int_kernel<<<(225000+255)/256,256,0,stream>>>(CUR, 225000);
  int egrid = (NE + 255)/256;
  count_int_kernel<<<egrid,256,0,stream>>>(e_ut_d, NE, cnt_ut);
  count_int_kernel<<<egrid,256,0,stream>>>(e_tm_d, NE, cnt_tm);
  count_int_kernel<<<egrid,256,0,stream>>>(e_mt_d, NE, cnt_mt);
  count_int_kernel<<<egrid,256,0,stream>>>(e_tu_d, NE, cnt_tu);
  auto nb = [](int n){ return (n + 1023)/1024; };
  block_reduce_kernel<<<nb(NTX),256,0,stream>>>(cnt_ut, NTX, bs_ut);
  block_reduce_kernel<<<nb(NMERCH),256,0,stream>>>(cnt_tm, NMERCH, bs_tm);
  block_reduce_kernel<<<nb(NTX),256,0,stream>>>(cnt_mt, NTX, bs_mt);
  block_reduce_kernel<<<nb(NUSER),256,0,stream>>>(cnt_tu, NUSER, bs_tu);
  scan_small_kernel<<<1,1,0,stream>>>(bs_ut, nb(NTX), rp_ut, NTX, NE);
  scan_small_kernel<<<1,1,0,stream>>>(bs_tm, nb(NMERCH), rp_tm, NMERCH, NE);
  scan_small_kernel<<<1,1,0,stream>>>(bs_mt, nb(NTX), rp_mt, NTX, NE);
  scan_small_kernel<<<1,1,0,stream>>>(bs_tu, nb(NUSER), rp_tu, NUSER, NE);
  scan_block_kernel<<<nb(NTX),256,0,stream>>>(cnt_ut, NTX, bs_ut, rp_ut, inv_ut);
  scan_block_kernel<<<nb(NMERCH),256,0,stream>>>(cnt_tm, NMERCH, bs_tm, rp_tm, inv_tm);
  scan_block_kernel<<<nb(NTX),256,0,stream>>>(cnt_mt, NTX, bs_mt, rp_mt, inv_mt);
  scan_block_kernel<<<nb(NUSER),256,0,stream>>>(cnt_tu, NUSER, bs_tu, rp_tu, inv_tu);
  fill_csr_kernel<<<egrid,256,0,stream>>>(e_ut_s, e_ut_d, rp_ut, cur_ut, SS_ut, NE);
  fill_csr_kernel<<<egrid,256,0,stream>>>(e_tm_s, e_tm_d, rp_tm, cur_tm, SS_tm, NE);
  fill_csr_kernel<<<egrid,256,0,stream>>>(e_mt_s, e_mt_d, rp_mt, cur_mt, SS_mt, NE);
  fill_csr_kernel<<<egrid,256,0,stream>>>(e_tu_s, e_tu_d, rp_tu, cur_tu, SS_tu, NE);

  // ---- weight prep (bf16, transposed) ----
  int wg = (65536+255)/256;
  tcvt_kernel<<<(8192+255)/256,256,0,stream>>>(Wp, WTp, 32, 256);
  for (int l = 0; l < 2; ++l){
    for (int r = 0; r < 4; ++r)
      tcvt_kernel<<<wg,256,0,stream>>>(Wl + (size_t)(l*4+r)*65536, WTl + (size_t)(l*4+r)*65536, 256, 256);
    tcvt_kernel<<<wg,256,0,stream>>>(Wr + (size_t)(l*4+1)*65536, WTr1 + (size_t)l*65536, 256, 256);
    tcvt_kernel<<<wg,256,0,stream>>>(Wr + (size_t)(l*4+3)*65536, WTr3 + (size_t)l*65536, 256, 256);
    tcvt2_kernel<<<wg,256,0,stream>>>(Wr + (size_t)(l*4+0)*65536, Wr + (size_t)(l*4+2)*65536,
                                      WT02 + (size_t)l*65536, 256, 256);
  }
  tcvtH_kernel<<<wg,256,0,stream>>>(Wc1, Wv1, WTH, 256);
  bh_kernel<<<1,256,0,stream>>>(bc1, bv1, bH);

  auto gg = [](int M){ return dim3((unsigned)((M+127)/128), 2); };

  // ---- init activations ----
  cvt_kernel<<<(NTX*32/4+255)/256,256,0,stream>>>(x_tx, XTin, NTX*32/4);
  mfma_gemm_kernel<true,true,false,false><<<gg(NTX),256,0,stream>>>(XTin, WTp, bp, nullptr, XT, NTX, 32, HD);
  cvt_kernel<<<(NUSER*HD/4+255)/256,256,0,stream>>>(x_user, XU0, NUSER*HD/4);
  cvt_kernel<<<(NMERCH*HD/4+255)/256,256,0,stream>>>(x_merch, XM0, NMERCH*HD/4);

  u16* xu_cur = XU0; u16* xu_nxt = XU1;
  u16* xm_cur = XM0; u16* xm_nxt = XM1;

  for (int l = 0; l < 2; ++l){
    const float* bl_l = bl + (size_t)l*4*256;
    u16* WTl_l = WTl + (size_t)l*4*65536;
    u16* Tu = (u16*)R1;
    u16* Tm = (u16*)R1 + (size_t)NUSER*HD;
    float* UOUT = (float*)R1;

    // inbound means of OLD XT into user/merchant (bf16 out)
    gather_mean_kernel<<<(NMERCH+3)/4,256,0,stream>>>(XT, rp_tm, SS_tm, inv_tm, AGGM, NMERCH);
    gather_mean_kernel<<<(NUSER+3)/4,256,0,stream>>>(XT, rp_tu, SS_tu, inv_tu, AGGU, NUSER);

    // transform-first for tx inbound
    mfma_gemm_kernel<true,false,false,false><<<gg(NUSER),256,0,stream>>>(xu_cur, WTl_l + 0*65536, nullptr, nullptr, Tu, NUSER, HD, HD);
    mfma_gemm_kernel<true,false,false,false><<<gg(NMERCH),256,0,stream>>>(xm_cur, WTl_l + 2*65536, nullptr, nullptr, Tm, NMERCH, HD, HD);

    // tx root term + fused epilogue -> new XT (in place; all reads of old XT done)
    mfma_gemm_kernel<true,false,false,false><<<gg(NTX),256,0,stream>>>(XT, WT02 + (size_t)l*65536, nullptr, nullptr, ACCb, NTX, HD, HD);
    fused_tx_kernel<<<(NTX+3)/4,256,0,stream>>>(ACCb, Tu, Tm,
        rp_ut, SS_ut, inv_ut, rp_mt, SS_mt, inv_mt,
        bl_l + 0*256, bl_l + 2*256, XT, NTX);

    // merchant: MOUT = AGGM@Wl1 + bl1 ; XM_new = bf16(relu(XM_old@Wr1 + MOUT))
    mfma_gemm_kernel<false,true,false,false><<<gg(NMERCH),256,0,stream>>>(AGGM, WTl_l + 1*65536, bl_l + 1*256, nullptr, MOUT, NMERCH, HD, HD);
    mfma_gemm_kernel<true,false,true,true><<<gg(NMERCH),256,0,stream>>>(xm_cur, WTr1 + (size_t)l*65536, nullptr, MOUT, xm_nxt, NMERCH, HD, HD);

    // user: UOUT = AGGU@Wl3 + bl3 (after fused_tx consumed Tu/Tm) ; XU_new = bf16(relu(XU_old@Wr3 + UOUT))
    mfma_gemm_kernel<false,true,false,false><<<gg(NUSER),256,0,stream>>>(AGGU, WTl_l + 3*65536, bl_l + 3*256, nullptr, UOUT, NUSER, HD, HD);
    mfma_gemm_kernel<true,false,true,true><<<gg(NUSER),256,0,stream>>>(xu_cur, WTr3 + (size_t)l*65536, nullptr, UOUT, xu_nxt, NUSER, HD, HD);

    { u16* tmp = xu_cur; xu_cur = xu_nxt; xu_nxt = tmp; }
    { u16* tmp = xm_cur; xm_cur = xm_nxt; xm_nxt = tmp; }
  }

  // heads
  mfma_gemm_kernel<true,true,true,false><<<gg(NTX),256,0,stream>>>(XT, WTH, bH, nullptr, ACCb, NTX, HD, HD);
  head_kernel<<<(NTX+3)/4,256,0,stream>>>(ACCb, Wc2, bc2, Wv2, bv2, out, NTX);
}

// Round 6
// 845.355 us; speedup vs baseline: 14.1782x; 1.3087x over previous
//
#include <hip/hip_runtime.h>

#define NTX 100000
#define NUSER 20000
#define NMERCH 5000
#define HD 256
#define ROWPAD 128

using u16 = unsigned short;
typedef __attribute__((ext_vector_type(8))) short bf16x8;
typedef __attribute__((ext_vector_type(4))) float f32x4;

__device__ __forceinline__ u16 f2bf(float f){
  unsigned u = __float_as_uint(f);
  unsigned r = (u + 0x7FFFu + ((u >> 16) & 1u)) >> 16;
  return (u16)r;
}
__device__ __forceinline__ float bf2f(u16 b){
  return __uint_as_float(((unsigned)b) << 16);
}

// MLP-optimized gather: cooperative index load + shfl broadcast + 4 independent chains.
__device__ __forceinline__ void gather4(const u16* __restrict__ T, const int* __restrict__ ss,
    int j0, int j1, int lane, int c, float& o0, float& o1, float& o2, float& o3){
  float a0=0,a1=0,a2=0,a3=0, b0=0,b1=0,b2=0,b3=0;
  float c0=0,c1=0,c2=0,c3=0, d0=0,d1=0,d2=0,d3=0;
  for (int base = j0; base < j1; base += 64){
    int n = j1 - base; if (n > 64) n = 64;
    int idx = ss[base + (lane < n ? lane : 0)];
    for (int jj = 0; jj < n; jj += 4){
      int s0 = __shfl(idx, jj);
      int s1 = __shfl(idx, jj+1);
      int s2 = __shfl(idx, jj+2);
      int s3 = __shfl(idx, jj+3);
      ushort4 v0 = *(const ushort4*)(T + (size_t)s0*HD + c);
      ushort4 v1 = *(const ushort4*)(T + (size_t)s1*HD + c);
      ushort4 v2 = *(const ushort4*)(T + (size_t)s2*HD + c);
      ushort4 v3 = *(const ushort4*)(T + (size_t)s3*HD + c);
      a0 += bf2f(v0.x); a1 += bf2f(v0.y); a2 += bf2f(v0.z); a3 += bf2f(v0.w);
      if (jj+1 < n){ b0 += bf2f(v1.x); b1 += bf2f(v1.y); b2 += bf2f(v1.z); b3 += bf2f(v1.w); }
      if (jj+2 < n){ c0 += bf2f(v2.x); c1 += bf2f(v2.y); c2 += bf2f(v2.z); c3 += bf2f(v2.w); }
      if (jj+3 < n){ d0 += bf2f(v3.x); d1 += bf2f(v3.y); d2 += bf2f(v3.z); d3 += bf2f(v3.w); }
    }
  }
  o0 += (a0+b0)+(c0+d0); o1 += (a1+b1)+(c1+d1);
  o2 += (a2+b2)+(c2+d2); o3 += (a3+b3)+(c3+d3);
}

// ---------------- fused CSR-build helpers (blockIdx.y = relation: 0=ut,1=tm,2=mt,3=tu) ----------------
__device__ __forceinline__ int rel_n(int y){ return y==0?NTX: y==1?NMERCH: y==2?NTX:NUSER; }
__device__ __forceinline__ int rel_coff(int y){ return y==0?0: y==1?100000: y==2?105000:205000; }
__device__ __forceinline__ int rel_rpoff(int y){ return y==0?0: y==1?100001: y==2?105002:205003; }

__global__ __launch_bounds__(256) void zero2_kernel(int* __restrict__ a, int* __restrict__ b, int n){
  int i = blockIdx.x*256 + threadIdx.x;
  if (i < n){ a[i] = 0; b[i] = 0; }
}

__global__ __launch_bounds__(256) void count4_kernel(const int* __restrict__ d0, const int* __restrict__ d1,
    const int* __restrict__ d2, const int* __restrict__ d3, int nE, int* __restrict__ CNT){
  int y = blockIdx.y;
  const int* d = y==0?d0: y==1?d1: y==2?d2:d3;
  int i = blockIdx.x*256 + threadIdx.x;
  if (i < nE) atomicAdd(&CNT[rel_coff(y) + d[i]], 1);
}

__global__ __launch_bounds__(256) void block_reduce4_kernel(const int* __restrict__ CNT, int* __restrict__ BS){
  int y = blockIdx.y;
  int n = rel_n(y);
  const int* cnt = CNT + rel_coff(y);
  __shared__ int sh[256];
  int b = blockIdx.x, t = threadIdx.x;
  int base = b*1024;
  int v = 0;
  for (int i = t; i < 1024; i += 256){ int idx = base + i; if (idx < n) v += cnt[idx]; }
  sh[t] = v; __syncthreads();
  for (int o = 128; o > 0; o >>= 1){ if (t < o) sh[t] += sh[t+o]; __syncthreads(); }
  if (t == 0) BS[y*128 + b] = sh[0];
}

__global__ void scan_small4_kernel(int* __restrict__ BS, int* __restrict__ RP, int nE){
  int t = threadIdx.x;
  if (t >= 4) return;
  int n = rel_n(t);
  int* bsum = BS + t*128;
  int nbb = (n + 1023)/1024;
  int run = 0;
  for (int i = 0; i < nbb; ++i){ int v = bsum[i]; bsum[i] = run; run += v; }
  RP[rel_rpoff(t) + n] = nE;
}

__global__ __launch_bounds__(256) void scan_block4_kernel(const int* __restrict__ CNT,
    const int* __restrict__ BS, int* __restrict__ RP, float* __restrict__ INV){
  int y = blockIdx.y;
  int n = rel_n(y);
  const int* cnt = CNT + rel_coff(y);
  int* rowptr = RP + rel_rpoff(y);
  float* inv = INV + rel_coff(y);
  __shared__ int sh[256];
  int b = blockIdx.x, t = threadIdx.x;
  int base = b*1024 + t*4;
  int c0=0,c1=0,c2=0,c3=0;
  if (base+0 < n) c0 = cnt[base+0];
  if (base+1 < n) c1 = cnt[base+1];
  if (base+2 < n) c2 = cnt[base+2];
  if (base+3 < n) c3 = cnt[base+3];
  int local = c0+c1+c2+c3;
  sh[t] = local; __syncthreads();
  for (int o = 1; o < 256; o <<= 1){
    int v = (t >= o) ? sh[t-o] : 0;
    __syncthreads();
    sh[t] += v;
    __syncthreads();
  }
  int ex = BS[y*128 + b] + sh[t] - local;
  if (base+0 < n){ rowptr[base+0] = ex;          inv[base+0] = 1.f/fmaxf((float)c0,1.f); }
  if (base+1 < n){ rowptr[base+1] = ex+c0;       inv[base+1] = 1.f/fmaxf((float)c1,1.f); }
  if (base+2 < n){ rowptr[base+2] = ex+c0+c1;    inv[base+2] = 1.f/fmaxf((float)c2,1.f); }
  if (base+3 < n){ rowptr[base+3] = ex+c0+c1+c2; inv[base+3] = 1.f/fmaxf((float)c3,1.f); }
}

__global__ __launch_bounds__(256) void fill4_kernel(
    const int* __restrict__ s0p, const int* __restrict__ d0p,
    const int* __restrict__ s1p, const int* __restrict__ d1p,
    const int* __restrict__ s2p, const int* __restrict__ d2p,
    const int* __restrict__ s3p, const int* __restrict__ d3p,
    const int* __restrict__ RP, int* __restrict__ CUR,
    int* __restrict__ ss0, int* __restrict__ ss1, int* __restrict__ ss2, int* __restrict__ ss3, int nE){
  int y = blockIdx.y;
  const int* src = y==0?s0p: y==1?s1p: y==2?s2p:s3p;
  const int* dst = y==0?d0p: y==1?d1p: y==2?d2p:d3p;
  int* ssrc = y==0?ss0: y==1?ss1: y==2?ss2:ss3;
  const int* rowptr = RP + rel_rpoff(y);
  int* cursor = CUR + rel_coff(y);
  int e = blockIdx.x*256 + threadIdx.x;
  if (e < nE){
    int d = dst[e];
    int pos = atomicAdd(&cursor[d], 1);
    ssrc[rowptr[d] + pos] = src[e];
  }
}

// ---------------- fused weight prep (grid.y = 0..15) ----------------
__global__ __launch_bounds__(256) void wprep_kernel(const float* __restrict__ Wl, const float* __restrict__ Wr,
    const float* __restrict__ Wp, const float* __restrict__ Wc1, const float* __restrict__ Wv1,
    const float* __restrict__ bc1, const float* __restrict__ bv1,
    u16* __restrict__ WTl, u16* __restrict__ WTr1, u16* __restrict__ WTr3, u16* __restrict__ WT02,
    u16* __restrict__ WTH, u16* __restrict__ WTp, float* __restrict__ bH){
  int y = blockIdx.y;
  int i = blockIdx.x*256 + threadIdx.x;
  if (y < 8){
    if (i < 65536){ int k=i>>8, n=i&255; WTl[(size_t)y*65536 + n*256 + k] = f2bf(Wl[(size_t)y*65536 + i]); }
  } else if (y < 10){
    int l = y-8;
    if (i < 65536){ int k=i>>8, n=i&255; WTr1[(size_t)l*65536 + n*256 + k] = f2bf(Wr[(size_t)(l*4+1)*65536 + i]); }
  } else if (y < 12){
    int l = y-10;
    if (i < 65536){ int k=i>>8, n=i&255; WTr3[(size_t)l*65536 + n*256 + k] = f2bf(Wr[(size_t)(l*4+3)*65536 + i]); }
  } else if (y < 14){
    int l = y-12;
    if (i < 65536){ int k=i>>8, n=i&255;
      WT02[(size_t)l*65536 + n*256 + k] = f2bf(Wr[(size_t)(l*4+0)*65536 + i] + Wr[(size_t)(l*4+2)*65536 + i]); }
  } else if (y == 14){
    if (i < 65536){ int k=i>>8, n=i&255;
      float v = (n < 128) ? Wc1[k*128 + n] : Wv1[k*128 + (n-128)];
      WTH[(size_t)n*256 + k] = f2bf(v); }
  } else {
    if (i < 8192){ int k=i>>8, n=i&255; WTp[(size_t)n*32 + k] = f2bf(Wp[i]); }
    if (i < 256) bH[i] = (i < 128) ? bc1[i] : bv1[i-128];
  }
}

// fused f32->bf16 conversions (y=0: x_tx 32-dim, y=1: x_user, y=2: x_merch)
// n4: y=0 -> 800000, y=1 -> 1280000, y=2 -> 320000. grid.x = 5000 covers max (1.28M).
__global__ __launch_bounds__(256) void cvt3_kernel(const float* __restrict__ xt, const float* __restrict__ xu,
    const float* __restrict__ xm, u16* __restrict__ XTin, u16* __restrict__ XU, u16* __restrict__ XM){
  int y = blockIdx.y;
  const float* in = y==0?xt: y==1?xu:xm;
  u16* out = y==0?XTin: y==1?XU:XM;
  int n4 = y==0?NTX*32/4: y==1?NUSER*HD/4:NMERCH*HD/4;
  int i = blockIdx.x*256 + threadIdx.x;
  if (i >= n4) return;
  float4 v = ((const float4*)in)[i];
  ushort4 o; o.x = f2bf(v.x); o.y = f2bf(v.y); o.z = f2bf(v.z); o.w = f2bf(v.w);
  ((ushort4*)out)[i] = o;
}

// ---------------- MFMA GEMM: C = epilogue(A[MxK]bf16 @ WT[NxK]bf16) ----------------
template<bool CBF, bool BIAS, bool RELU, bool ACCUM>
__global__ __launch_bounds__(256) void mfma_gemm_kernel(const u16* __restrict__ A, const u16* __restrict__ BT,
    const float* __restrict__ bias, const float* __restrict__ Cadd, void* __restrict__ Cp, int M, int K, int N){
  __shared__ u16 As[128][40];
  __shared__ u16 Bs[128][40];
  int m0 = blockIdx.x * 128, n0 = blockIdx.y * 128;
  int t = threadIdx.x;
  int w = t >> 6, lane = t & 63;
  int wm = (w >> 1) << 6, wn = (w & 1) << 6;
  int lm = lane & 15;
  int lk = (lane >> 4) << 3;
  f32x4 acc[4][4] = {};

  int sr0 = t >> 2,        sk0 = (t & 3) << 3;
  int sr1 = (t+256) >> 2,  sk1 = sk0;

  for (int k0 = 0; k0 < K; k0 += 32){
    uint4 a0 = *(const uint4*)(A  + (size_t)(m0+sr0)*K + k0 + sk0);
    uint4 a1 = *(const uint4*)(A  + (size_t)(m0+sr1)*K + k0 + sk1);
    uint4 b0 = *(const uint4*)(BT + (size_t)(n0+sr0)*K + k0 + sk0);
    uint4 b1 = *(const uint4*)(BT + (size_t)(n0+sr1)*K + k0 + sk1);
    *(uint4*)&As[sr0][sk0] = a0;
    *(uint4*)&As[sr1][sk1] = a1;
    *(uint4*)&Bs[sr0][sk0] = b0;
    *(uint4*)&Bs[sr1][sk1] = b1;
    __syncthreads();
    bf16x8 af[4], bf[4];
    #pragma unroll
    for (int i = 0; i < 4; ++i) af[i] = *(const bf16x8*)&As[wm + i*16 + lm][lk];
    #pragma unroll
    for (int j = 0; j < 4; ++j) bf[j] = *(const bf16x8*)&Bs[wn + j*16 + lm][lk];
    #pragma unroll
    for (int i = 0; i < 4; ++i)
      #pragma unroll
      for (int j = 0; j < 4; ++j)
        acc[i][j] = __builtin_amdgcn_mfma_f32_16x16x32_bf16(af[i], bf[j], acc[i][j], 0, 0, 0);
    __syncthreads();
  }

  int rsub = (lane >> 4) << 2;
  #pragma unroll
  for (int j = 0; j < 4; ++j){
    int col = n0 + wn + j*16 + lm;
    float bv = 0.f;
    if constexpr (BIAS) bv = bias[col];
    #pragma unroll
    for (int i = 0; i < 4; ++i){
      int rbase = m0 + wm + i*16 + rsub;
      #pragma unroll
      for (int r = 0; r < 4; ++r){
        int row = rbase + r;
        if (row < M){
          float v = acc[i][j][r] + bv;
          if constexpr (ACCUM) v += Cadd[(size_t)row*N + col];
          if constexpr (RELU) v = fmaxf(v, 0.f);
          if constexpr (CBF) ((u16*)Cp)[(size_t)row*N + col] = f2bf(v);
          else               ((float*)Cp)[(size_t)row*N + col] = v;
        }
      }
    }
  }
}

// ---------------- gather-mean: out[d] = bf16(inv[d] * sum_j X[ss[j]]) ----------------
__global__ __launch_bounds__(256) void gather_mean_kernel(const u16* __restrict__ X,
    const int* __restrict__ rp, const int* __restrict__ ss, const float* __restrict__ inv,
    u16* __restrict__ out, int M){
  int d = blockIdx.x*4 + (threadIdx.x >> 6);
  if (d >= M) return;
  int lane = threadIdx.x & 63;
  int c = lane << 2;
  int j0 = rp[d], j1 = rp[d+1];
  float o0=0,o1=0,o2=0,o3=0;
  gather4(X, ss, j0, j1, lane, c, o0, o1, o2, o3);
  float sc = inv[d];
  ushort4 o; o.x = f2bf(o0*sc); o.y = f2bf(o1*sc); o.z = f2bf(o2*sc); o.w = f2bf(o3*sc);
  *(ushort4*)(out + (size_t)d*HD + c) = o;
}

// ---------------- fused tx epilogue ----------------
__global__ __launch_bounds__(256) void fused_tx_kernel(const u16* __restrict__ ACCb,
    const u16* __restrict__ Tu, const u16* __restrict__ Tm,
    const int* __restrict__ rpu, const int* __restrict__ ssu, const float* __restrict__ invu,
    const int* __restrict__ rpm, const int* __restrict__ ssm, const float* __restrict__ invm,
    const float* __restrict__ b0, const float* __restrict__ b2, u16* __restrict__ XT, int M){
  int d = blockIdx.x*4 + (threadIdx.x >> 6);
  if (d >= M) return;
  int lane = threadIdx.x & 63;
  int c = lane << 2;
  ushort4 av = *(const ushort4*)(ACCb + (size_t)d*HD + c);
  float r0 = bf2f(av.x), r1 = bf2f(av.y), r2 = bf2f(av.z), r3 = bf2f(av.w);
  {
    float s0=0,s1=0,s2=0,s3=0;
    gather4(Tu, ssu, rpu[d], rpu[d+1], lane, c, s0, s1, s2, s3);
    float sc = invu[d];
    r0 += s0*sc; r1 += s1*sc; r2 += s2*sc; r3 += s3*sc;
  }
  {
    float s0=0,s1=0,s2=0,s3=0;
    gather4(Tm, ssm, rpm[d], rpm[d+1], lane, c, s0, s1, s2, s3);
    float sc = invm[d];
    r0 += s0*sc; r1 += s1*sc; r2 += s2*sc; r3 += s3*sc;
  }
  float4 bb0 = *(const float4*)(b0 + c);
  float4 bb2 = *(const float4*)(b2 + c);
  ushort4 o;
  o.x = f2bf(fmaxf(0.5f*(r0 + bb0.x + bb2.x), 0.f));
  o.y = f2bf(fmaxf(0.5f*(r1 + bb0.y + bb2.y), 0.f));
  o.z = f2bf(fmaxf(0.5f*(r2 + bb0.z + bb2.z), 0.f));
  o.w = f2bf(fmaxf(0.5f*(r3 + bb0.w + bb2.w), 0.f));
  *(ushort4*)(XT + (size_t)d*HD + c) = o;
}

// ---------------- head ----------------
__global__ __launch_bounds__(256) void head_kernel(const u16* __restrict__ Hm, const float* __restrict__ Wc2,
    const float* __restrict__ bc2, const float* __restrict__ Wv2, const float* __restrict__ bv2,
    float* __restrict__ out, int M){
  int row = blockIdx.x*4 + (threadIdx.x >> 6);
  if (row >= M) return;
  int lane = threadIdx.x & 63;
  const u16* h = Hm + (size_t)row*256;
  float s1 = bf2f(h[lane])*Wc2[lane] + bf2f(h[lane+64])*Wc2[lane+64];
  float s2 = bf2f(h[128+lane])*Wv2[lane] + bf2f(h[192+lane])*Wv2[lane+64];
  #pragma unroll
  for (int off = 32; off > 0; off >>= 1){
    s1 += __shfl_down(s1, off);
    s2 += __shfl_down(s2, off);
  }
  if (lane == 0){ out[row] = s1 + bc2[0]; out[M+row] = s2 + bv2[0]; }
}

extern "C" void kernel_launch(void* const* d_in, const int* in_sizes, int n_in,
                              void* d_out, int out_size, void* d_ws, size_t ws_size,
                              hipStream_t stream){
  const float* x_tx   = (const float*)d_in[0];
  const float* x_user = (const float*)d_in[1];
  const float* x_merch= (const float*)d_in[2];
  const float* Wp  = (const float*)d_in[3];
  const float* bp  = (const float*)d_in[4];
  const float* Wl  = (const float*)d_in[5];
  const float* bl  = (const float*)d_in[6];
  const float* Wr  = (const float*)d_in[7];
  const float* Wc1 = (const float*)d_in[8];
  const float* bc1 = (const float*)d_in[9];
  const float* Wc2 = (const float*)d_in[10];
  const float* bc2 = (const float*)d_in[11];
  const float* Wv1 = (const float*)d_in[12];
  const float* bv1 = (const float*)d_in[13];
  const float* Wv2 = (const float*)d_in[14];
  const float* bv2 = (const float*)d_in[15];
  const int* e_ut_s = (const int*)d_in[16];
  const int* e_ut_d = (const int*)d_in[17];
  const int* e_tm_s = (const int*)d_in[18];
  const int* e_tm_d = (const int*)d_in[19];
  const int* e_mt_s = (const int*)d_in[20];
  const int* e_mt_d = (const int*)d_in[21];
  const int* e_tu_s = (const int*)d_in[22];
  const int* e_tu_d = (const int*)d_in[23];
  float* out = (float*)d_out;
  const int NE = in_sizes[16];

  // ---- workspace layout (~181 MB) ----
  char* p = (char*)d_ws;
  auto take = [&](size_t bytes)->char*{ char* r = p; p += (bytes + 255) & ~(size_t)255; return r; };
  u16*   XT    = (u16*)  take((size_t)(NTX+ROWPAD)*HD*2);
  u16*   ACCb  = (u16*)  take((size_t)(NTX+ROWPAD)*HD*2);
  char*  R1    =         take((size_t)NUSER*HD*4);
  u16*   AGGU  = (u16*)  take((size_t)(NUSER+ROWPAD)*HD*2);
  u16*   AGGM  = (u16*)  take((size_t)(NMERCH+ROWPAD)*HD*2);
  float* MOUT  = (float*)take((size_t)NMERCH*HD*4);
  u16*   XU0   = (u16*)  take((size_t)(NUSER+ROWPAD)*HD*2);
  u16*   XU1   = (u16*)  take((size_t)(NUSER+ROWPAD)*HD*2);
  u16*   XM0   = (u16*)  take((size_t)(NMERCH+ROWPAD)*HD*2);
  u16*   XM1   = (u16*)  take((size_t)(NMERCH+ROWPAD)*HD*2);
  int*   CNT   = (int*)  take((size_t)225000*4);
  int*   CUR   = (int*)  take((size_t)225000*4);
  float* INV   = (float*)take((size_t)225000*4);
  int*   RP    = (int*)  take((size_t)225008*4);
  int*   SS_ut = (int*)  take((size_t)NE*4);
  int*   SS_tm = (int*)  take((size_t)NE*4);
  int*   SS_mt = (int*)  take((size_t)NE*4);
  int*   SS_tu = (int*)  take((size_t)NE*4);
  int*   BS    = (int*)  take((size_t)4*128*4);
  u16*   WTp   = (u16*)  take((size_t)32*256*2);
  u16*   WTl   = (u16*)  take((size_t)8*65536*2);
  u16*   WTr1  = (u16*)  take((size_t)2*65536*2);
  u16*   WTr3  = (u16*)  take((size_t)2*65536*2);
  u16*   WT02  = (u16*)  take((size_t)2*65536*2);
  u16*   WTH   = (u16*)  take((size_t)65536*2);
  float* bH    = (float*)take((size_t)256*4);
  u16*   XTin  = ACCb;   // alias: [NTX][32] bf16, consumed by proj GEMM before ACCb first written

  float* inv_ut = INV,  *inv_tm = INV+100000, *inv_mt = INV+105000, *inv_tu = INV+205000;
  int*   rp_ut  = RP,   *rp_tm  = RP+100001,  *rp_mt  = RP+105002,  *rp_tu  = RP+205003;

  // ---- CSR build (fused across relations) ----
  int egrid = (NE + 255)/256;
  zero2_kernel<<<(225000+255)/256,256,0,stream>>>(CNT, CUR, 225000);
  count4_kernel<<<dim3(egrid,4),256,0,stream>>>(e_ut_d, e_tm_d, e_mt_d, e_tu_d, NE, CNT);
  block_reduce4_kernel<<<dim3(98,4),256,0,stream>>>(CNT, BS);
  scan_small4_kernel<<<1,4,0,stream>>>(BS, RP, NE);
  scan_block4_kernel<<<dim3(98,4),256,0,stream>>>(CNT, BS, RP, INV);
  fill4_kernel<<<dim3(egrid,4),256,0,stream>>>(e_ut_s, e_ut_d, e_tm_s, e_tm_d, e_mt_s, e_mt_d,
      e_tu_s, e_tu_d, RP, CUR, SS_ut, SS_tm, SS_mt, SS_tu, NE);

  // ---- weight prep (one launch) ----
  wprep_kernel<<<dim3(256,16),256,0,stream>>>(Wl, Wr, Wp, Wc1, Wv1, bc1, bv1,
      WTl, WTr1, WTr3, WT02, WTH, WTp, bH);

  auto gg = [](int M){ return dim3((unsigned)((M+127)/128), 2); };

  // ---- init activations ----
  cvt3_kernel<<<dim3(5000,3),256,0,stream>>>(x_tx, x_user, x_merch, XTin, XU0, XM0);
  mfma_gemm_kernel<true,true,false,false><<<gg(NTX),256,0,stream>>>(XTin, WTp, bp, nullptr, XT, NTX, 32, HD);

  u16* xu_cur = XU0; u16* xu_nxt = XU1;
  u16* xm_cur = XM0; u16* xm_nxt = XM1;

  for (int l = 0; l < 2; ++l){
    const float* bl_l = bl + (size_t)l*4*256;
    u16* WTl_l = WTl + (size_t)l*4*65536;
    u16* Tu = (u16*)R1;
    u16* Tm = (u16*)R1 + (size_t)NUSER*HD;
    float* UOUT = (float*)R1;

    // inbound means of OLD XT into user/merchant (bf16 out)
    gather_mean_kernel<<<(NMERCH+3)/4,256,0,stream>>>(XT, rp_tm, SS_tm, inv_tm, AGGM, NMERCH);
    gather_mean_kernel<<<(NUSER+3)/4,256,0,stream>>>(XT, rp_tu, SS_tu, inv_tu, AGGU, NUSER);

    // transform-first for tx inbound
    mfma_gemm_kernel<true,false,false,false><<<gg(NUSER),256,0,stream>>>(xu_cur, WTl_l + 0*65536, nullptr, nullptr, Tu, NUSER, HD, HD);
    mfma_gemm_kernel<true,false,false,false><<<gg(NMERCH),256,0,stream>>>(xm_cur, WTl_l + 2*65536, nullptr, nullptr, Tm, NMERCH, HD, HD);

    // tx root term + fused epilogue -> new XT (in place; all reads of old XT done)
    mfma_gemm_kernel<true,false,false,false><<<gg(NTX),256,0,stream>>>(XT, WT02 + (size_t)l*65536, nullptr, nullptr, ACCb, NTX, HD, HD);
    fused_tx_kernel<<<(NTX+3)/4,256,0,stream>>>(ACCb, Tu, Tm,
        rp_ut, SS_ut, inv_ut, rp_mt, SS_mt, inv_mt,
        bl_l + 0*256, bl_l + 2*256, XT, NTX);

    // merchant
    mfma_gemm_kernel<false,true,false,false><<<gg(NMERCH),256,0,stream>>>(AGGM, WTl_l + 1*65536, bl_l + 1*256, nullptr, MOUT, NMERCH, HD, HD);
    mfma_gemm_kernel<true,false,true,true><<<gg(NMERCH),256,0,stream>>>(xm_cur, WTr1 + (size_t)l*65536, nullptr, MOUT, xm_nxt, NMERCH, HD, HD);

    // user
    mfma_gemm_kernel<false,true,false,false><<<gg(NUSER),256,0,stream>>>(AGGU, WTl_l + 3*65536, bl_l + 3*256, nullptr, UOUT, NUSER, HD, HD);
    mfma_gemm_kernel<true,false,true,true><<<gg(NUSER),256,0,stream>>>(xu_cur, WTr3 + (size_t)l*65536, nullptr, UOUT, xu_nxt, NUSER, HD, HD);

    { u16* tmp = xu_cur; xu_cur = xu_nxt; xu_nxt = tmp; }
    { u16* tmp = xm_cur; xm_cur = xm_nxt; xm_nxt = tmp; }
  }

  // heads
  mfma_gemm_kernel<true,true,true,false><<<gg(NTX),256,0,stream>>>(XT, WTH, bH, nullptr, ACCb, NTX, HD, HD);
  head_kernel<<<(NTX+3)/4,256,0,stream>>>(ACCb, Wc2, bc2, Wv2, bv2, out, NTX);
}

// Round 7
// 693.540 us; speedup vs baseline: 17.2818x; 1.2189x over previous
//
#include <hip/hip_runtime.h>

#define NTX 100000
#define NUSER 20000
#define NMERCH 5000
#define HD 256
#define ROWPAD 128

using u16 = unsigned short;
typedef __attribute__((ext_vector_type(8))) short bf16x8;
typedef __attribute__((ext_vector_type(4))) float f32x4;

__device__ __forceinline__ u16 f2bf(float f){
  unsigned u = __float_as_uint(f);
  unsigned r = (u + 0x7FFFu + ((u >> 16) & 1u)) >> 16;
  return (u16)r;
}
__device__ __forceinline__ float bf2f(u16 b){
  return __uint_as_float(((unsigned)b) << 16);
}
__device__ __forceinline__ unsigned pk2(float a, float b){
  return (unsigned)f2bf(a) | ((unsigned)f2bf(b) << 16);
}

// MLP-optimized gather: cooperative index load + shfl broadcast + 4 independent chains.
__device__ __forceinline__ void gather4(const u16* __restrict__ T, const int* __restrict__ ss,
    int j0, int j1, int lane, int c, float& o0, float& o1, float& o2, float& o3){
  float a0=0,a1=0,a2=0,a3=0, b0=0,b1=0,b2=0,b3=0;
  float c0=0,c1=0,c2=0,c3=0, d0=0,d1=0,d2=0,d3=0;
  for (int base = j0; base < j1; base += 64){
    int n = j1 - base; if (n > 64) n = 64;
    int idx = ss[base + (lane < n ? lane : 0)];
    for (int jj = 0; jj < n; jj += 4){
      int s0 = __shfl(idx, jj);
      int s1 = __shfl(idx, jj+1);
      int s2 = __shfl(idx, jj+2);
      int s3 = __shfl(idx, jj+3);
      ushort4 v0 = *(const ushort4*)(T + (size_t)s0*HD + c);
      ushort4 v1 = *(const ushort4*)(T + (size_t)s1*HD + c);
      ushort4 v2 = *(const ushort4*)(T + (size_t)s2*HD + c);
      ushort4 v3 = *(const ushort4*)(T + (size_t)s3*HD + c);
      a0 += bf2f(v0.x); a1 += bf2f(v0.y); a2 += bf2f(v0.z); a3 += bf2f(v0.w);
      if (jj+1 < n){ b0 += bf2f(v1.x); b1 += bf2f(v1.y); b2 += bf2f(v1.z); b3 += bf2f(v1.w); }
      if (jj+2 < n){ c0 += bf2f(v2.x); c1 += bf2f(v2.y); c2 += bf2f(v2.z); c3 += bf2f(v2.w); }
      if (jj+3 < n){ d0 += bf2f(v3.x); d1 += bf2f(v3.y); d2 += bf2f(v3.z); d3 += bf2f(v3.w); }
    }
  }
  o0 += (a0+b0)+(c0+d0); o1 += (a1+b1)+(c1+d1);
  o2 += (a2+b2)+(c2+d2); o3 += (a3+b3)+(c3+d3);
}

// ---------------- fused CSR-build helpers (blockIdx.y = relation: 0=ut,1=tm,2=mt,3=tu) ----------------
__device__ __forceinline__ int rel_n(int y){ return y==0?NTX: y==1?NMERCH: y==2?NTX:NUSER; }
__device__ __forceinline__ int rel_coff(int y){ return y==0?0: y==1?100000: y==2?105000:205000; }
__device__ __forceinline__ int rel_rpoff(int y){ return y==0?0: y==1?100001: y==2?105002:205003; }

__global__ __launch_bounds__(256) void zero2_kernel(int* __restrict__ a, int* __restrict__ b, int n){
  int i = blockIdx.x*256 + threadIdx.x;
  if (i < n){ a[i] = 0; b[i] = 0; }
}

__global__ __launch_bounds__(256) void count4_kernel(const int* __restrict__ d0, const int* __restrict__ d1,
    const int* __restrict__ d2, const int* __restrict__ d3, int nE, int* __restrict__ CNT){
  int y = blockIdx.y;
  const int* d = y==0?d0: y==1?d1: y==2?d2:d3;
  int i = blockIdx.x*256 + threadIdx.x;
  if (i < nE) atomicAdd(&CNT[rel_coff(y) + d[i]], 1);
}

__global__ __launch_bounds__(256) void block_reduce4_kernel(const int* __restrict__ CNT, int* __restrict__ BS){
  int y = blockIdx.y;
  int n = rel_n(y);
  const int* cnt = CNT + rel_coff(y);
  __shared__ int sh[256];
  int b = blockIdx.x, t = threadIdx.x;
  int base = b*1024;
  int v = 0;
  for (int i = t; i < 1024; i += 256){ int idx = base + i; if (idx < n) v += cnt[idx]; }
  sh[t] = v; __syncthreads();
  for (int o = 128; o > 0; o >>= 1){ if (t < o) sh[t] += sh[t+o]; __syncthreads(); }
  if (t == 0) BS[y*128 + b] = sh[0];
}

__global__ void scan_small4_kernel(int* __restrict__ BS, int* __restrict__ RP, int nE){
  int t = threadIdx.x;
  if (t >= 4) return;
  int n = rel_n(t);
  int* bsum = BS + t*128;
  int nbb = (n + 1023)/1024;
  int run = 0;
  for (int i = 0; i < nbb; ++i){ int v = bsum[i]; bsum[i] = run; run += v; }
  RP[rel_rpoff(t) + n] = nE;
}

__global__ __launch_bounds__(256) void scan_block4_kernel(const int* __restrict__ CNT,
    const int* __restrict__ BS, int* __restrict__ RP, float* __restrict__ INV){
  int y = blockIdx.y;
  int n = rel_n(y);
  const int* cnt = CNT + rel_coff(y);
  int* rowptr = RP + rel_rpoff(y);
  float* inv = INV + rel_coff(y);
  __shared__ int sh[256];
  int b = blockIdx.x, t = threadIdx.x;
  int base = b*1024 + t*4;
  int c0=0,c1=0,c2=0,c3=0;
  if (base+0 < n) c0 = cnt[base+0];
  if (base+1 < n) c1 = cnt[base+1];
  if (base+2 < n) c2 = cnt[base+2];
  if (base+3 < n) c3 = cnt[base+3];
  int local = c0+c1+c2+c3;
  sh[t] = local; __syncthreads();
  for (int o = 1; o < 256; o <<= 1){
    int v = (t >= o) ? sh[t-o] : 0;
    __syncthreads();
    sh[t] += v;
    __syncthreads();
  }
  int ex = BS[y*128 + b] + sh[t] - local;
  if (base+0 < n){ rowptr[base+0] = ex;          inv[base+0] = 1.f/fmaxf((float)c0,1.f); }
  if (base+1 < n){ rowptr[base+1] = ex+c0;       inv[base+1] = 1.f/fmaxf((float)c1,1.f); }
  if (base+2 < n){ rowptr[base+2] = ex+c0+c1;    inv[base+2] = 1.f/fmaxf((float)c2,1.f); }
  if (base+3 < n){ rowptr[base+3] = ex+c0+c1+c2; inv[base+3] = 1.f/fmaxf((float)c3,1.f); }
}

__global__ __launch_bounds__(256) void fill4_kernel(
    const int* __restrict__ s0p, const int* __restrict__ d0p,
    const int* __restrict__ s1p, const int* __restrict__ d1p,
    const int* __restrict__ s2p, const int* __restrict__ d2p,
    const int* __restrict__ s3p, const int* __restrict__ d3p,
    const int* __restrict__ RP, int* __restrict__ CUR,
    int* __restrict__ ss0, int* __restrict__ ss1, int* __restrict__ ss2, int* __restrict__ ss3, int nE){
  int y = blockIdx.y;
  const int* src = y==0?s0p: y==1?s1p: y==2?s2p:s3p;
  const int* dst = y==0?d0p: y==1?d1p: y==2?d2p:d3p;
  int* ssrc = y==0?ss0: y==1?ss1: y==2?ss2:ss3;
  const int* rowptr = RP + rel_rpoff(y);
  int* cursor = CUR + rel_coff(y);
  int e = blockIdx.x*256 + threadIdx.x;
  if (e < nE){
    int d = dst[e];
    int pos = atomicAdd(&cursor[d], 1);
    ssrc[rowptr[d] + pos] = src[e];
  }
}

// ---------------- fused weight prep (grid.y = 0..15) ----------------
__global__ __launch_bounds__(256) void wprep_kernel(const float* __restrict__ Wl, const float* __restrict__ Wr,
    const float* __restrict__ Wp, const float* __restrict__ Wc1, const float* __restrict__ Wv1,
    const float* __restrict__ bc1, const float* __restrict__ bv1,
    u16* __restrict__ WTl, u16* __restrict__ WTr1, u16* __restrict__ WTr3, u16* __restrict__ WT02,
    u16* __restrict__ WTH, u16* __restrict__ WTp, float* __restrict__ bH){
  int y = blockIdx.y;
  int i = blockIdx.x*256 + threadIdx.x;
  if (y < 8){
    if (i < 65536){ int k=i>>8, n=i&255; WTl[(size_t)y*65536 + n*256 + k] = f2bf(Wl[(size_t)y*65536 + i]); }
  } else if (y < 10){
    int l = y-8;
    if (i < 65536){ int k=i>>8, n=i&255; WTr1[(size_t)l*65536 + n*256 + k] = f2bf(Wr[(size_t)(l*4+1)*65536 + i]); }
  } else if (y < 12){
    int l = y-10;
    if (i < 65536){ int k=i>>8, n=i&255; WTr3[(size_t)l*65536 + n*256 + k] = f2bf(Wr[(size_t)(l*4+3)*65536 + i]); }
  } else if (y < 14){
    int l = y-12;
    if (i < 65536){ int k=i>>8, n=i&255;
      WT02[(size_t)l*65536 + n*256 + k] = f2bf(Wr[(size_t)(l*4+0)*65536 + i] + Wr[(size_t)(l*4+2)*65536 + i]); }
  } else if (y == 14){
    if (i < 65536){ int k=i>>8, n=i&255;
      float v = (n < 128) ? Wc1[k*128 + n] : Wv1[k*128 + (n-128)];
      WTH[(size_t)n*256 + k] = f2bf(v); }
  } else {
    if (i < 8192){ int k=i>>8, n=i&255; WTp[(size_t)n*32 + k] = f2bf(Wp[i]); }
    if (i < 256) bH[i] = (i < 128) ? bc1[i] : bv1[i-128];
  }
}

// fused f32->bf16 conversions (y=0: x_user, y=1: x_merch); grid.x=5000 covers 1.28M float4s
__global__ __launch_bounds__(256) void cvt2_kernel(const float* __restrict__ xu,
    const float* __restrict__ xm, u16* __restrict__ XU, u16* __restrict__ XM){
  int y = blockIdx.y;
  const float* in = y==0?xu:xm;
  u16* out = y==0?XU:XM;
  int n4 = y==0?NUSER*HD/4:NMERCH*HD/4;
  int i = blockIdx.x*256 + threadIdx.x;
  if (i >= n4) return;
  float4 v = ((const float4*)in)[i];
  ushort4 o; o.x = f2bf(v.x); o.y = f2bf(v.y); o.z = f2bf(v.z); o.w = f2bf(v.w);
  ((ushort4*)out)[i] = o;
}

// ---------------- proj GEMM: XT = bf16(x_tx[f32, Mx32] @ WTp[256x32] + bp) ----------------
__global__ __launch_bounds__(256) void proj_gemm_kernel(const float* __restrict__ A, const u16* __restrict__ WT,
    const float* __restrict__ bias, u16* __restrict__ C, int M){
  __shared__ u16 As[128][40];
  __shared__ u16 Bs[128][40];
  int m0 = blockIdx.x * 128, n0 = blockIdx.y * 128;
  int t = threadIdx.x;
  int w = t >> 6, lane = t & 63;
  int wm = (w >> 1) << 6, wn = (w & 1) << 6;
  int lm = lane & 15;
  int lk = (lane >> 4) << 3;
  int sr = t >> 1, sc = (t & 1) << 4;
  // stage A rows (f32 -> bf16), guarded (input buffer has no padding)
  float4 f0 = {0,0,0,0}, f1 = {0,0,0,0}, f2 = {0,0,0,0}, f3 = {0,0,0,0};
  if (m0 + sr < M){
    const float* ap = A + (size_t)(m0+sr)*32 + sc;
    f0 = *(const float4*)(ap+0); f1 = *(const float4*)(ap+4);
    f2 = *(const float4*)(ap+8); f3 = *(const float4*)(ap+12);
  }
  uint4 q0, q1;
  q0.x = pk2(f0.x,f0.y); q0.y = pk2(f0.z,f0.w); q0.z = pk2(f1.x,f1.y); q0.w = pk2(f1.z,f1.w);
  q1.x = pk2(f2.x,f2.y); q1.y = pk2(f2.z,f2.w); q1.z = pk2(f3.x,f3.y); q1.w = pk2(f3.z,f3.w);
  *(uint4*)&As[sr][sc] = q0;
  *(uint4*)&As[sr][sc+8] = q1;
  // stage B rows (WT is [256][32] bf16)
  const u16* bp_ = WT + (size_t)(n0+sr)*32 + sc;
  *(uint4*)&Bs[sr][sc]   = *(const uint4*)(bp_);
  *(uint4*)&Bs[sr][sc+8] = *(const uint4*)(bp_ + 8);
  __syncthreads();
  bf16x8 af[4], bf[4];
  #pragma unroll
  for (int i = 0; i < 4; ++i) af[i] = *(const bf16x8*)&As[wm + i*16 + lm][lk];
  #pragma unroll
  for (int j = 0; j < 4; ++j) bf[j] = *(const bf16x8*)&Bs[wn + j*16 + lm][lk];
  f32x4 acc[4][4] = {};
  #pragma unroll
  for (int i = 0; i < 4; ++i)
    #pragma unroll
    for (int j = 0; j < 4; ++j)
      acc[i][j] = __builtin_amdgcn_mfma_f32_16x16x32_bf16(af[i], bf[j], acc[i][j], 0, 0, 0);
  int rsub = (lane >> 4) << 2;
  #pragma unroll
  for (int j = 0; j < 4; ++j){
    int col = n0 + wn + j*16 + lm;
    float bv = bias[col];
    #pragma unroll
    for (int i = 0; i < 4; ++i){
      int rbase = m0 + wm + i*16 + rsub;
      #pragma unroll
      for (int r = 0; r < 4; ++r){
        int row = rbase + r;
        if (row < M) C[(size_t)row*HD + col] = f2bf(acc[i][j][r] + bv);
      }
    }
  }
}

// ---------------- generic MFMA GEMM (used for tx root + head) ----------------
template<bool CBF, bool BIAS, bool RELU, bool ACCUM>
__global__ __launch_bounds__(256) void mfma_gemm_kernel(const u16* __restrict__ A, const u16* __restrict__ BT,
    const float* __restrict__ bias, const float* __restrict__ Cadd, void* __restrict__ Cp, int M, int K, int N){
  __shared__ u16 As[128][40];
  __shared__ u16 Bs[128][40];
  int m0 = blockIdx.x * 128, n0 = blockIdx.y * 128;
  int t = threadIdx.x;
  int w = t >> 6, lane = t & 63;
  int wm = (w >> 1) << 6, wn = (w & 1) << 6;
  int lm = lane & 15;
  int lk = (lane >> 4) << 3;
  f32x4 acc[4][4] = {};
  int sr0 = t >> 2,        sk0 = (t & 3) << 3;
  int sr1 = (t+256) >> 2,  sk1 = sk0;
  for (int k0 = 0; k0 < K; k0 += 32){
    uint4 a0 = *(const uint4*)(A  + (size_t)(m0+sr0)*K + k0 + sk0);
    uint4 a1 = *(const uint4*)(A  + (size_t)(m0+sr1)*K + k0 + sk1);
    uint4 b0 = *(const uint4*)(BT + (size_t)(n0+sr0)*K + k0 + sk0);
    uint4 b1 = *(const uint4*)(BT + (size_t)(n0+sr1)*K + k0 + sk1);
    *(uint4*)&As[sr0][sk0] = a0;
    *(uint4*)&As[sr1][sk1] = a1;
    *(uint4*)&Bs[sr0][sk0] = b0;
    *(uint4*)&Bs[sr1][sk1] = b1;
    __syncthreads();
    bf16x8 af[4], bf[4];
    #pragma unroll
    for (int i = 0; i < 4; ++i) af[i] = *(const bf16x8*)&As[wm + i*16 + lm][lk];
    #pragma unroll
    for (int j = 0; j < 4; ++j) bf[j] = *(const bf16x8*)&Bs[wn + j*16 + lm][lk];
    #pragma unroll
    for (int i = 0; i < 4; ++i)
      #pragma unroll
      for (int j = 0; j < 4; ++j)
        acc[i][j] = __builtin_amdgcn_mfma_f32_16x16x32_bf16(af[i], bf[j], acc[i][j], 0, 0, 0);
    __syncthreads();
  }
  int rsub = (lane >> 4) << 2;
  #pragma unroll
  for (int j = 0; j < 4; ++j){
    int col = n0 + wn + j*16 + lm;
    float bv = 0.f;
    if constexpr (BIAS) bv = bias[col];
    #pragma unroll
    for (int i = 0; i < 4; ++i){
      int rbase = m0 + wm + i*16 + rsub;
      #pragma unroll
      for (int r = 0; r < 4; ++r){
        int row = rbase + r;
        if (row < M){
          float v = acc[i][j][r] + bv;
          if constexpr (ACCUM) v += Cadd[(size_t)row*N + col];
          if constexpr (RELU) v = fmaxf(v, 0.f);
          if constexpr (CBF) ((u16*)Cp)[(size_t)row*N + col] = f2bf(v);
          else               ((float*)Cp)[(size_t)row*N + col] = v;
        }
      }
    }
  }
}

// ---------------- batched transform GEMM (z=0: Tu=XU@W0T, z=1: Tm=XM@W2T), K=N=256 ----------------
__global__ __launch_bounds__(256) void pair_gemm_kernel(
    const u16* __restrict__ A0, const u16* __restrict__ W0, u16* __restrict__ C0, int M0,
    const u16* __restrict__ A1, const u16* __restrict__ W1, u16* __restrict__ C1, int M1){
  int z = blockIdx.z;
  const u16* A = z ? A1 : A0;
  const u16* WT = z ? W1 : W0;
  u16* C = z ? C1 : C0;
  int M = z ? M1 : M0;
  int m0 = blockIdx.x * 128, n0 = blockIdx.y * 128;
  if (m0 >= M) return;
  __shared__ u16 As[128][40];
  __shared__ u16 Bs[128][40];
  int t = threadIdx.x;
  int w = t >> 6, lane = t & 63;
  int wm = (w >> 1) << 6, wn = (w & 1) << 6;
  int lm = lane & 15;
  int lk = (lane >> 4) << 3;
  f32x4 acc[4][4] = {};
  int sr0 = t >> 2,        sk0 = (t & 3) << 3;
  int sr1 = (t+256) >> 2,  sk1 = sk0;
  for (int k0 = 0; k0 < 256; k0 += 32){
    uint4 a0 = *(const uint4*)(A  + (size_t)(m0+sr0)*256 + k0 + sk0);
    uint4 a1 = *(const uint4*)(A  + (size_t)(m0+sr1)*256 + k0 + sk1);
    uint4 b0 = *(const uint4*)(WT + (size_t)(n0+sr0)*256 + k0 + sk0);
    uint4 b1 = *(const uint4*)(WT + (size_t)(n0+sr1)*256 + k0 + sk1);
    *(uint4*)&As[sr0][sk0] = a0;
    *(uint4*)&As[sr1][sk1] = a1;
    *(uint4*)&Bs[sr0][sk0] = b0;
    *(uint4*)&Bs[sr1][sk1] = b1;
    __syncthreads();
    bf16x8 af[4], bf[4];
    #pragma unroll
    for (int i = 0; i < 4; ++i) af[i] = *(const bf16x8*)&As[wm + i*16 + lm][lk];
    #pragma unroll
    for (int j = 0; j < 4; ++j) bf[j] = *(const bf16x8*)&Bs[wn + j*16 + lm][lk];
    #pragma unroll
    for (int i = 0; i < 4; ++i)
      #pragma unroll
      for (int j = 0; j < 4; ++j)
        acc[i][j] = __builtin_amdgcn_mfma_f32_16x16x32_bf16(af[i], bf[j], acc[i][j], 0, 0, 0);
    __syncthreads();
  }
  int rsub = (lane >> 4) << 2;
  #pragma unroll
  for (int j = 0; j < 4; ++j){
    int col = n0 + wn + j*16 + lm;
    #pragma unroll
    for (int i = 0; i < 4; ++i){
      int rbase = m0 + wm + i*16 + rsub;
      #pragma unroll
      for (int r = 0; r < 4; ++r){
        int row = rbase + r;
        if (row < M) C[(size_t)row*256 + col] = f2bf(acc[i][j][r]);
      }
    }
  }
}

// ---------------- batched update GEMM: X_new = bf16(relu(AGG@WlT + Xold@WrT + b)), virtual K=512 ----------------
__global__ __launch_bounds__(256) void pair_gemm2_kernel(
    const u16* __restrict__ G0, const u16* __restrict__ X0, const u16* __restrict__ Wa0, const u16* __restrict__ Wb0,
    const float* __restrict__ b0, u16* __restrict__ C0, int M0,
    const u16* __restrict__ G1, const u16* __restrict__ X1, const u16* __restrict__ Wa1, const u16* __restrict__ Wb1,
    const float* __restrict__ b1, u16* __restrict__ C1, int M1){
  int z = blockIdx.z;
  const u16* G  = z ? G1 : G0;
  const u16* X  = z ? X1 : X0;
  const u16* Wa = z ? Wa1 : Wa0;
  const u16* Wb = z ? Wb1 : Wb0;
  const float* bias = z ? b1 : b0;
  u16* C = z ? C1 : C0;
  int M = z ? M1 : M0;
  int m0 = blockIdx.x * 128, n0 = blockIdx.y * 128;
  if (m0 >= M) return;
  __shared__ u16 As[128][40];
  __shared__ u16 Bs[128][40];
  int t = threadIdx.x;
  int w = t >> 6, lane = t & 63;
  int wm = (w >> 1) << 6, wn = (w & 1) << 6;
  int lm = lane & 15;
  int lk = (lane >> 4) << 3;
  f32x4 acc[4][4] = {};
  int sr0 = t >> 2,        sk0 = (t & 3) << 3;
  int sr1 = (t+256) >> 2,  sk1 = sk0;
  for (int k0 = 0; k0 < 512; k0 += 32){
    const u16* A  = (k0 < 256) ? G : X;
    const u16* WT = (k0 < 256) ? Wa : Wb;
    int kk = k0 & 255;
    uint4 a0 = *(const uint4*)(A  + (size_t)(m0+sr0)*256 + kk + sk0);
    uint4 a1 = *(const uint4*)(A  + (size_t)(m0+sr1)*256 + kk + sk1);
    uint4 b0_ = *(const uint4*)(WT + (size_t)(n0+sr0)*256 + kk + sk0);
    uint4 b1_ = *(const uint4*)(WT + (size_t)(n0+sr1)*256 + kk + sk1);
    *(uint4*)&As[sr0][sk0] = a0;
    *(uint4*)&As[sr1][sk1] = a1;
    *(uint4*)&Bs[sr0][sk0] = b0_;
    *(uint4*)&Bs[sr1][sk1] = b1_;
    __syncthreads();
    bf16x8 af[4], bf[4];
    #pragma unroll
    for (int i = 0; i < 4; ++i) af[i] = *(const bf16x8*)&As[wm + i*16 + lm][lk];
    #pragma unroll
    for (int j = 0; j < 4; ++j) bf[j] = *(const bf16x8*)&Bs[wn + j*16 + lm][lk];
    #pragma unroll
    for (int i = 0; i < 4; ++i)
      #pragma unroll
      for (int j = 0; j < 4; ++j)
        acc[i][j] = __builtin_amdgcn_mfma_f32_16x16x32_bf16(af[i], bf[j], acc[i][j], 0, 0, 0);
    __syncthreads();
  }
  int rsub = (lane >> 4) << 2;
  #pragma unroll
  for (int j = 0; j < 4; ++j){
    int col = n0 + wn + j*16 + lm;
    float bv = bias[col];
    #pragma unroll
    for (int i = 0; i < 4; ++i){
      int rbase = m0 + wm + i*16 + rsub;
      #pragma unroll
      for (int r = 0; r < 4; ++r){
        int row = rbase + r;
        if (row < M) C[(size_t)row*256 + col] = f2bf(fmaxf(acc[i][j][r] + bv, 0.f));
      }
    }
  }
}

// ---------------- batched gather-mean (y=0: tm -> AGGM, y=1: tu -> AGGU) ----------------
__global__ __launch_bounds__(256) void gather_pair_kernel(const u16* __restrict__ XT,
    const int* __restrict__ rp0, const int* __restrict__ ss0, const float* __restrict__ inv0,
    u16* __restrict__ out0, int M0,
    const int* __restrict__ rp1, const int* __restrict__ ss1, const float* __restrict__ inv1,
    u16* __restrict__ out1, int M1){
  int y = blockIdx.y;
  const int* rp = y ? rp1 : rp0;
  const int* ss = y ? ss1 : ss0;
  const float* inv = y ? inv1 : inv0;
  u16* out = y ? out1 : out0;
  int M = y ? M1 : M0;
  int d = blockIdx.x*4 + (threadIdx.x >> 6);
  if (d >= M) return;
  int lane = threadIdx.x & 63;
  int c = lane << 2;
  float o0=0,o1=0,o2=0,o3=0;
  gather4(XT, ss, rp[d], rp[d+1], lane, c, o0, o1, o2, o3);
  float sc = inv[d];
  ushort4 o; o.x = f2bf(o0*sc); o.y = f2bf(o1*sc); o.z = f2bf(o2*sc); o.w = f2bf(o3*sc);
  *(ushort4*)(out + (size_t)d*HD + c) = o;
}

// ---------------- fused tx epilogue ----------------
__global__ __launch_bounds__(256) void fused_tx_kernel(const u16* __restrict__ ACCb,
    const u16* __restrict__ Tu, const u16* __restrict__ Tm,
    const int* __restrict__ rpu, const int* __restrict__ ssu, const float* __restrict__ invu,
    const int* __restrict__ rpm, const int* __restrict__ ssm, const float* __restrict__ invm,
    const float* __restrict__ b0, const float* __restrict__ b2, u16* __restrict__ XT, int M){
  int d = blockIdx.x*4 + (threadIdx.x >> 6);
  if (d >= M) return;
  int lane = threadIdx.x & 63;
  int c = lane << 2;
  ushort4 av = *(const ushort4*)(ACCb + (size_t)d*HD + c);
  float r0 = bf2f(av.x), r1 = bf2f(av.y), r2 = bf2f(av.z), r3 = bf2f(av.w);
  {
    float s0=0,s1=0,s2=0,s3=0;
    gather4(Tu, ssu, rpu[d], rpu[d+1], lane, c, s0, s1, s2, s3);
    float sc = invu[d];
    r0 += s0*sc; r1 += s1*sc; r2 += s2*sc; r3 += s3*sc;
  }
  {
    float s0=0,s1=0,s2=0,s3=0;
    gather4(Tm, ssm, rpm[d], rpm[d+1], lane, c, s0, s1, s2, s3);
    float sc = invm[d];
    r0 += s0*sc; r1 += s1*sc; r2 += s2*sc; r3 += s3*sc;
  }
  float4 bb0 = *(const float4*)(b0 + c);
  float4 bb2 = *(const float4*)(b2 + c);
  ushort4 o;
  o.x = f2bf(fmaxf(0.5f*(r0 + bb0.x + bb2.x), 0.f));
  o.y = f2bf(fmaxf(0.5f*(r1 + bb0.y + bb2.y), 0.f));
  o.z = f2bf(fmaxf(0.5f*(r2 + bb0.z + bb2.z), 0.f));
  o.w = f2bf(fmaxf(0.5f*(r3 + bb0.w + bb2.w), 0.f));
  *(ushort4*)(XT + (size_t)d*HD + c) = o;
}

// ---------------- head ----------------
__global__ __launch_bounds__(256) void head_kernel(const u16* __restrict__ Hm, const float* __restrict__ Wc2,
    const float* __restrict__ bc2, const float* __restrict__ Wv2, const float* __restrict__ bv2,
    float* __restrict__ out, int M){
  int row = blockIdx.x*4 + (threadIdx.x >> 6);
  if (row >= M) return;
  int lane = threadIdx.x & 63;
  const u16* h = Hm + (size_t)row*256;
  float s1 = bf2f(h[lane])*Wc2[lane] + bf2f(h[lane+64])*Wc2[lane+64];
  float s2 = bf2f(h[128+lane])*Wv2[lane] + bf2f(h[192+lane])*Wv2[lane+64];
  #pragma unroll
  for (int off = 32; off > 0; off >>= 1){
    s1 += __shfl_down(s1, off);
    s2 += __shfl_down(s2, off);
  }
  if (lane == 0){ out[row] = s1 + bc2[0]; out[M+row] = s2 + bv2[0]; }
}

extern "C" void kernel_launch(void* const* d_in, const int* in_sizes, int n_in,
                              void* d_out, int out_size, void* d_ws, size_t ws_size,
                              hipStream_t stream){
  const float* x_tx   = (const float*)d_in[0];
  const float* x_user = (const float*)d_in[1];
  const float* x_merch= (const float*)d_in[2];
  const float* Wp  = (const float*)d_in[3];
  const float* bp  = (const float*)d_in[4];
  const float* Wl  = (const float*)d_in[5];
  const float* bl  = (const float*)d_in[6];
  const float* Wr  = (const float*)d_in[7];
  const float* Wc1 = (const float*)d_in[8];
  const float* bc1 = (const float*)d_in[9];
  const float* Wc2 = (const float*)d_in[10];
  const float* bc2 = (const float*)d_in[11];
  const float* Wv1 = (const float*)d_in[12];
  const float* bv1 = (const float*)d_in[13];
  const float* Wv2 = (const float*)d_in[14];
  const float* bv2 = (const float*)d_in[15];
  const int* e_ut_s = (const int*)d_in[16];
  const int* e_ut_d = (const int*)d_in[17];
  const int* e_tm_s = (const int*)d_in[18];
  const int* e_tm_d = (const int*)d_in[19];
  const int* e_mt_s = (const int*)d_in[20];
  const int* e_mt_d = (const int*)d_in[21];
  const int* e_tu_s = (const int*)d_in[22];
  const int* e_tu_d = (const int*)d_in[23];
  float* out = (float*)d_out;
  const int NE = in_sizes[16];

  // ---- workspace layout (~170 MB) ----
  char* p = (char*)d_ws;
  auto take = [&](size_t bytes)->char*{ char* r = p; p += (bytes + 255) & ~(size_t)255; return r; };
  u16*   XT    = (u16*)  take((size_t)(NTX+ROWPAD)*HD*2);
  u16*   ACCb  = (u16*)  take((size_t)(NTX+ROWPAD)*HD*2);
  u16*   Tu    = (u16*)  take((size_t)NUSER*HD*2);
  u16*   Tm    = (u16*)  take((size_t)NMERCH*HD*2);
  u16*   AGGU  = (u16*)  take((size_t)(NUSER+ROWPAD)*HD*2);
  u16*   AGGM  = (u16*)  take((size_t)(NMERCH+ROWPAD)*HD*2);
  u16*   XU0   = (u16*)  take((size_t)(NUSER+ROWPAD)*HD*2);
  u16*   XU1   = (u16*)  take((size_t)(NUSER+ROWPAD)*HD*2);
  u16*   XM0   = (u16*)  take((size_t)(NMERCH+ROWPAD)*HD*2);
  u16*   XM1   = (u16*)  take((size_t)(NMERCH+ROWPAD)*HD*2);
  int*   CNT   = (int*)  take((size_t)225000*4);
  int*   CUR   = (int*)  take((size_t)225000*4);
  float* INV   = (float*)take((size_t)225000*4);
  int*   RP    = (int*)  take((size_t)225008*4);
  int*   SS_ut = (int*)  take((size_t)NE*4);
  int*   SS_tm = (int*)  take((size_t)NE*4);
  int*   SS_mt = (int*)  take((size_t)NE*4);
  int*   SS_tu = (int*)  take((size_t)NE*4);
  int*   BS    = (int*)  take((size_t)4*128*4);
  u16*   WTp   = (u16*)  take((size_t)32*256*2);
  u16*   WTl   = (u16*)  take((size_t)8*65536*2);
  u16*   WTr1  = (u16*)  take((size_t)2*65536*2);
  u16*   WTr3  = (u16*)  take((size_t)2*65536*2);
  u16*   WT02  = (u16*)  take((size_t)2*65536*2);
  u16*   WTH   = (u16*)  take((size_t)65536*2);
  float* bH    = (float*)take((size_t)256*4);

  float* inv_ut = INV,  *inv_tm = INV+100000, *inv_mt = INV+105000, *inv_tu = INV+205000;
  int*   rp_ut  = RP,   *rp_tm  = RP+100001,  *rp_mt  = RP+105002,  *rp_tu  = RP+205003;

  // ---- CSR build (fused across relations) ----
  int egrid = (NE + 255)/256;
  zero2_kernel<<<(225000+255)/256,256,0,stream>>>(CNT, CUR, 225000);
  count4_kernel<<<dim3(egrid,4),256,0,stream>>>(e_ut_d, e_tm_d, e_mt_d, e_tu_d, NE, CNT);
  block_reduce4_kernel<<<dim3(98,4),256,0,stream>>>(CNT, BS);
  scan_small4_kernel<<<1,4,0,stream>>>(BS, RP, NE);
  scan_block4_kernel<<<dim3(98,4),256,0,stream>>>(CNT, BS, RP, INV);
  fill4_kernel<<<dim3(egrid,4),256,0,stream>>>(e_ut_s, e_ut_d, e_tm_s, e_tm_d, e_mt_s, e_mt_d,
      e_tu_s, e_tu_d, RP, CUR, SS_ut, SS_tm, SS_mt, SS_tu, NE);

  // ---- weight prep (one launch) ----
  wprep_kernel<<<dim3(256,16),256,0,stream>>>(Wl, Wr, Wp, Wc1, Wv1, bc1, bv1,
      WTl, WTr1, WTr3, WT02, WTH, WTp, bH);

  // ---- init activations ----
  cvt2_kernel<<<dim3(5000,2),256,0,stream>>>(x_user, x_merch, XU0, XM0);
  proj_gemm_kernel<<<dim3(782,2),256,0,stream>>>(x_tx, WTp, bp, XT, NTX);

  u16* xu_cur = XU0; u16* xu_nxt = XU1;
  u16* xm_cur = XM0; u16* xm_nxt = XM1;

  for (int l = 0; l < 2; ++l){
    const float* bl_l = bl + (size_t)l*4*256;
    u16* WTl_l = WTl + (size_t)l*4*65536;

    // inbound means of OLD XT into merchant/user (batched)
    gather_pair_kernel<<<dim3(5000,2),256,0,stream>>>(XT,
        rp_tm, SS_tm, inv_tm, AGGM, NMERCH,
        rp_tu, SS_tu, inv_tu, AGGU, NUSER);

    // transform-first for tx inbound (batched: Tu = XU@Wl0, Tm = XM@Wl2)
    pair_gemm_kernel<<<dim3(157,2,2),256,0,stream>>>(
        xu_cur, WTl_l + 0*65536, Tu, NUSER,
        xm_cur, WTl_l + 2*65536, Tm, NMERCH);

    // tx root term + fused epilogue -> new XT (in place; all reads of old XT done)
    mfma_gemm_kernel<true,false,false,false><<<dim3(782,2),256,0,stream>>>(
        XT, WT02 + (size_t)l*65536, nullptr, nullptr, ACCb, NTX, 256, 256);
    fused_tx_kernel<<<(NTX+3)/4,256,0,stream>>>(ACCb, Tu, Tm,
        rp_ut, SS_ut, inv_ut, rp_mt, SS_mt, inv_mt,
        bl_l + 0*256, bl_l + 2*256, XT, NTX);

    // user/merchant updates (batched, virtual K=512, fused bias+relu+bf16)
    pair_gemm2_kernel<<<dim3(157,2,2),256,0,stream>>>(
        AGGU, xu_cur, WTl_l + 3*65536, WTr3 + (size_t)l*65536, bl_l + 3*256, xu_nxt, NUSER,
        AGGM, xm_cur, WTl_l + 1*65536, WTr1 + (size_t)l*65536, bl_l + 1*256, xm_nxt, NMERCH);

    { u16* tmp = xu_cur; xu_cur = xu_nxt; xu_nxt = tmp; }
    { u16* tmp = xm_cur; xm_cur = xm_nxt; xm_nxt = tmp; }
  }

  // heads
  mfma_gemm_kernel<true,true,true,false><<<dim3(782,2),256,0,stream>>>(
      XT, WTH, bH, nullptr, ACCb, NTX, 256, 256);
  head_kernel<<<(NTX+3)/4,256,0,stream>>>(ACCb, Wc2, bc2, Wv2, bv2, out, NTX);
}